// Round 15
// baseline (476.939 us; speedup 1.0000x reference)
//
#include <hip/hip_runtime.h>
#include <cstdint>

#define DEV __device__ __forceinline__

typedef __attribute__((ext_vector_type(8))) short bf16x8;
typedef __attribute__((ext_vector_type(4))) float f32x4;
typedef __attribute__((ext_vector_type(16))) float f32x16;

#define MFMA(a,b,c) __builtin_amdgcn_mfma_f32_16x16x32_bf16((a),(b),(c),0,0,0)
#define MFMA32(a,b,c) __builtin_amdgcn_mfma_f32_32x32x16_bf16((a),(b),(c),0,0,0)

DEV unsigned short f2bf(float f) {
  union { float f; unsigned u; } v; v.f = f;
  unsigned r = v.u + 0x7fffu + ((v.u >> 16) & 1u);
  return (unsigned short)(r >> 16);
}
DEV float bf2f(unsigned short s) {
  union { unsigned u; float f; } v; v.u = ((unsigned)s) << 16; return v.f;
}
DEV float max3f(float a, float b, float c) { return fmaxf(fmaxf(a, b), c); }

// async global->LDS, 16B per lane. LDS dest is wave-uniform base + lane*16.
DEV void gload16(const unsigned short* g, short* l) {
  __builtin_amdgcn_global_load_lds(
      (const __attribute__((address_space(1))) unsigned*)g,
      (__attribute__((address_space(3))) unsigned*)l, 16, 0, 0);
}

// ---------------- prep kernels ----------------

// Ut[proj*512 + h*32 + r][d] = U_proj[h][d][r]  (bf16, B^T layout for stage-1)
__global__ void k_build_ut(const float* __restrict__ Uq, const float* __restrict__ Uk,
                           const float* __restrict__ Uv, unsigned short* __restrict__ Ut) {
  __shared__ float tile[32][33];
  int s = blockIdx.y;            // 0..47 = proj*16 + h
  int proj = s >> 4, h = s & 15;
  const float* U = (proj == 0) ? Uq : (proj == 1) ? Uk : Uv;
  const float* Us = U + (size_t)h * 1024 * 32;
  int d0 = blockIdx.x * 32;
  int tx = threadIdx.x, ty = threadIdx.y;
#pragma unroll
  for (int i = ty; i < 32; i += 8)
    tile[i][tx] = Us[(size_t)(d0 + i) * 32 + tx];
  __syncthreads();
#pragma unroll
  for (int i = ty; i < 32; i += 8)
    Ut[(size_t)(s * 32 + i) * 1024 + d0 + tx] = f2bf(tile[tx][i]);
}

// Vt[ph][dh][r] = V_proj[h][r][dh]  (bf16 B^T for stage-2), ph = proj*16 + h
__global__ void k_build_vt(const float* __restrict__ Vq, const float* __restrict__ Vk,
                           const float* __restrict__ Vv, unsigned short* __restrict__ Vt) {
  int ph = blockIdx.x;
  int proj = ph >> 4, h = ph & 15;
  const float* V = (proj == 0) ? Vq : (proj == 1) ? Vk : Vv;
  const float* Vs = V + (size_t)h * 2048;
  int t = threadIdx.x;
#pragma unroll
  for (int idx = t; idx < 2048; idx += 256) {
    int dh = idx >> 5, r = idx & 31;
    Vt[(size_t)ph * 2048 + idx] = f2bf(Vs[r * 64 + dh]);
  }
}

__global__ void k_f2bf(const float* __restrict__ in, unsigned short* __restrict__ out, int n) {
  int i = blockIdx.x * 256 + threadIdx.x;
  if (i < n) out[i] = f2bf(in[i]);
}

// fp32 [R][C] -> bf16 [C][R]
__global__ void k_transpose_bf16(const float* __restrict__ in, unsigned short* __restrict__ out,
                                 int R, int C) {
  __shared__ float tile[32][33];
  int c0 = blockIdx.x * 32, r0 = blockIdx.y * 32;
  int tx = threadIdx.x, ty = threadIdx.y;
#pragma unroll
  for (int i = ty; i < 32; i += 8)
    tile[i][tx] = in[(size_t)(r0 + i) * C + c0 + tx];
  __syncthreads();
#pragma unroll
  for (int i = ty; i < 32; i += 8)
    out[(size_t)(c0 + i) * R + r0 + tx] = f2bf(tile[tx][i]);
}

// ---------------- layernorm: one WAVE per row (4 rows/block, no barrier) ----------------
__global__ __launch_bounds__(256) void k_layernorm(const float* __restrict__ x,
                                                   const float* __restrict__ w,
                                                   const float* __restrict__ b,
                                                   unsigned short* __restrict__ out) {
  int lane = threadIdx.x & 63, wid = threadIdx.x >> 6;
  size_t row = (size_t)blockIdx.x * 4 + wid;
  const float4* xr = (const float4*)(x + row * 1024);
  float4 v[4];
  float s = 0.f, s2 = 0.f;
#pragma unroll
  for (int t = 0; t < 4; ++t) {
    v[t] = xr[lane + t * 64];
    s += v[t].x + v[t].y + v[t].z + v[t].w;
    s2 += v[t].x * v[t].x + v[t].y * v[t].y + v[t].z * v[t].z + v[t].w * v[t].w;
  }
#pragma unroll
  for (int o = 1; o < 64; o <<= 1) { s += __shfl_xor(s, o); s2 += __shfl_xor(s2, o); }
  float mean = s * (1.f / 1024.f);
  float var = s2 * (1.f / 1024.f) - mean * mean;
  float inv = rsqrtf(var + 1e-5f);
  unsigned long long* op = (unsigned long long*)(out + row * 1024);
#pragma unroll
  for (int t = 0; t < 4; ++t) {
    float4 wv = ((const float4*)w)[lane + t * 64];
    float4 bv = ((const float4*)b)[lane + t * 64];
    union { unsigned short u[4]; unsigned long long ll; } o;
    o.u[0] = f2bf((v[t].x - mean) * inv * wv.x + bv.x);
    o.u[1] = f2bf((v[t].y - mean) * inv * wv.y + bv.y);
    o.u[2] = f2bf((v[t].z - mean) * inv * wv.z + bv.z);
    o.u[3] = f2bf((v[t].w - mean) * inv * wv.w + bv.w);
    op[lane + t * 64] = o.ll;
  }
}

// ---------------- GEMM (BK=32): C[8192 x N] = A * Bt^T ----------------
// EPI 0: bf16 out;  1: bf16 out + bias;  2: f32 out + bias + resid
// LB(256,4): 4 blocks/CU (LDS 16KB, ~110 VGPR) to hide the barrier-drain stall.
template <int EPI>
__global__ __launch_bounds__(256, 4) void k_gemm(const unsigned short* __restrict__ A,
                                                 const unsigned short* __restrict__ Bt,
                                                 const float* __restrict__ bias,
                                                 const float* __restrict__ resid,
                                                 void* __restrict__ outp, int N, int K) {
  __shared__ short Al[128 * 32];
  __shared__ short Bl[128 * 32];
  int tid = threadIdx.x, lane = tid & 63, wid = tid >> 6;
  int wr = wid >> 1, wc = wid & 1;
  size_t row0 = (size_t)blockIdx.y * 128;
  int col0 = blockIdx.x * 128;
  int arow = lane >> 2, acol = (lane & 3) << 3;
  const unsigned short* Ag = A + (row0 + wid * 32 + arow) * K + acol;
  const unsigned short* Bg = Bt + ((size_t)(col0 + wid * 32 + arow)) * K + acol;
  short* Ald = Al + wid * 1024;
  short* Bld = Bl + wid * 1024;
  f32x4 acc[4][4] = {};
  int fr = lane & 15, fk = (lane >> 4) << 3;
  for (int k0 = 0; k0 < K; k0 += 32) {
    __syncthreads();
    gload16(Ag + k0, Ald);
    gload16(Ag + (size_t)16 * K + k0, Ald + 512);
    gload16(Bg + k0, Bld);
    gload16(Bg + (size_t)16 * K + k0, Bld + 512);
    __syncthreads();
    bf16x8 af[4], bfr[4];
#pragma unroll
    for (int i = 0; i < 4; ++i) {
      af[i] = *(const bf16x8*)&Al[(wr * 64 + i * 16 + fr) * 32 + fk];
      bfr[i] = *(const bf16x8*)&Bl[(wc * 64 + i * 16 + fr) * 32 + fk];
    }
#pragma unroll
    for (int i = 0; i < 4; ++i)
#pragma unroll
      for (int j = 0; j < 4; ++j) acc[i][j] = MFMA(af[i], bfr[j], acc[i][j]);
  }
  int cr = (lane >> 4) << 2, cc = lane & 15;
#pragma unroll
  for (int j = 0; j < 4; ++j) {
    int col = col0 + wc * 64 + j * 16 + cc;
    float bb = (EPI >= 1) ? bias[col] : 0.f;
#pragma unroll
    for (int i = 0; i < 4; ++i) {
#pragma unroll
      for (int r = 0; r < 4; ++r) {
        size_t row = row0 + wr * 64 + i * 16 + cr + r;
        float v = acc[i][j][r] + bb;
        if (EPI == 2)
          ((float*)outp)[row * N + col] = v + resid[row * N + col];
        else
          ((unsigned short*)outp)[row * N + col] = f2bf(v);
      }
    }
  }
}

// ---------------- fused QKV (BK=32 stage-1): xr = xn @ Ut^T, then per-head
// rank-32 expansion + bias + RoPE; V heads written DIRECTLY to vT (transposed).
__global__ __launch_bounds__(256, 2) void k_qkv(const unsigned short* __restrict__ A,
                                                const unsigned short* __restrict__ Ut,
                                                const unsigned short* __restrict__ Vt,
                                                const float* __restrict__ bq,
                                                const float* __restrict__ bk,
                                                const float* __restrict__ bv,
                                                unsigned short* __restrict__ qkv,
                                                unsigned short* __restrict__ vT) {
  __shared__ short Al[128 * 32];
  __shared__ short Bl[128 * 32];
  __shared__ short Xr[4][64 * 72];
  const int K = 1024, N3 = 3072;
  int tid = threadIdx.x, lane = tid & 63, wid = tid >> 6;
  int wr = wid >> 1, wc = wid & 1;
  size_t row0 = (size_t)blockIdx.y * 128;
  int col0 = blockIdx.x * 128;
  int arow = lane >> 2, acol = (lane & 3) << 3;
  const unsigned short* Ag = A + (row0 + wid * 32 + arow) * K + acol;
  const unsigned short* Bg = Ut + ((size_t)(col0 + wid * 32 + arow)) * K + acol;
  short* Ald = Al + wid * 1024;
  short* Bld = Bl + wid * 1024;
  f32x4 acc[4][4] = {};
  int fr = lane & 15, fk = (lane >> 4) << 3;
  for (int k0 = 0; k0 < K; k0 += 32) {
    __syncthreads();
    gload16(Ag + k0, Ald);
    gload16(Ag + (size_t)16 * K + k0, Ald + 512);
    gload16(Bg + k0, Bld);
    gload16(Bg + (size_t)16 * K + k0, Bld + 512);
    __syncthreads();
    bf16x8 af[4], bfr[4];
#pragma unroll
    for (int i = 0; i < 4; ++i) {
      af[i] = *(const bf16x8*)&Al[(wr * 64 + i * 16 + fr) * 32 + fk];
      bfr[i] = *(const bf16x8*)&Bl[(wc * 64 + i * 16 + fr) * 32 + fk];
    }
#pragma unroll
    for (int i = 0; i < 4; ++i)
#pragma unroll
      for (int j = 0; j < 4; ++j) acc[i][j] = MFMA(af[i], bfr[j], acc[i][j]);
  }
  int cr = (lane >> 4) << 2, cc = lane & 15;
  // bounce xr quadrant (bf16) into per-wave LDS [64 rows][72 cols]
  short* xw = &Xr[wid][0];
#pragma unroll
  for (int j = 0; j < 4; ++j)
#pragma unroll
    for (int i = 0; i < 4; ++i)
#pragma unroll
      for (int r = 0; r < 4; ++r)
        xw[(i * 16 + cr + r) * 72 + j * 16 + cc] = (short)f2bf(acc[i][j][r]);
  // same-wave write->read; compiler inserts lgkmcnt ordering
  int phbase = blockIdx.x * 4 + wc * 2;
  const f32x4 zero4 = {0.f, 0.f, 0.f, 0.f};
#pragma unroll
  for (int h2 = 0; h2 < 2; ++h2) {
    int ph = phbase + h2;
    int proj = ph >> 4, hh = ph & 15;
    bf16x8 af2[4], bf2[4];
#pragma unroll
    for (int i2 = 0; i2 < 4; ++i2)
      af2[i2] = *(const bf16x8*)&xw[(i2 * 16 + fr) * 72 + h2 * 32 + fk];
#pragma unroll
    for (int j2 = 0; j2 < 4; ++j2)
      bf2[j2] = *(const bf16x8*)(Vt + ((size_t)ph * 64 + j2 * 16 + fr) * 32 + fk);
    f32x4 a2[4][4];
#pragma unroll
    for (int i2 = 0; i2 < 4; ++i2)
#pragma unroll
      for (int j2 = 0; j2 < 4; ++j2) a2[i2][j2] = MFMA(af2[i2], bf2[j2], zero4);
    const float* bp = (proj == 0) ? bq : (proj == 1) ? bk : bv;
    if (proj == 2) {  // V: bias + DIRECT transposed write to vT[bh][dh][tok]
      int bq_ = (int)(row0 >> 11);
      int tok0 = (int)(row0 & 2047) + wr * 64;
      unsigned short* vtb = vT + ((size_t)(bq_ * 16 + hh) * 64) * 2048;
#pragma unroll
      for (int j2 = 0; j2 < 4; ++j2) {
        int dh = j2 * 16 + cc;
        float bb = bp[hh * 64 + dh];
        unsigned short* vrow = vtb + (size_t)dh * 2048;
#pragma unroll
        for (int i2 = 0; i2 < 4; ++i2) {
          union { unsigned short u[4]; unsigned long long ll; } o;
#pragma unroll
          for (int r = 0; r < 4; ++r) o.u[r] = f2bf(a2[i2][j2][r] + bb);
          *(unsigned long long*)(vrow + tok0 + i2 * 16 + cr) = o.ll;
        }
      }
    } else {  // Q/K: rotate pairs (dh, dh+32); Q folds 0.125*log2(e)
      int obase = proj * 1024 + hh * 64;
      float sc = (proj == 0) ? 0.18033688011112042f : 1.f;
#pragma unroll
      for (int j2 = 0; j2 < 2; ++j2) {
        int irot = j2 * 16 + cc;  // 0..31
        float freq = __expf((float)irot * -0.28782313662425575f);  // ln(1e4)/32
        float bb1 = bp[hh * 64 + irot];
        float bb2 = bp[hh * 64 + irot + 32];
#pragma unroll
        for (int i2 = 0; i2 < 4; ++i2)
#pragma unroll
          for (int r = 0; r < 4; ++r) {
            size_t row = row0 + wr * 64 + i2 * 16 + cr + r;
            int m = (int)(row & 2047);
            float x1v = a2[i2][j2][r] + bb1;
            float x2v = a2[i2][j2 + 2][r] + bb2;
            float sn, csn;
            __sincosf((float)m * freq, &sn, &csn);
            qkv[row * N3 + obase + irot] = f2bf((x1v * csn - x2v * sn) * sc);
            qkv[row * N3 + obase + irot + 32] = f2bf((x2v * csn + x1v * sn) * sc);
          }
      }
    }
  }
}

// ---------------- GEMM + GEGLU (BK=32): g = gelu_tanh(h1) * h2 ----------------
// 128 acc VGPRs -> stays at LB(256,2); (256,4) would force spills.
__global__ __launch_bounds__(256, 2) void k_gemm_geglu(const unsigned short* __restrict__ A,
                                                       const unsigned short* __restrict__ Bt,
                                                       const float* __restrict__ bias,
                                                       unsigned short* __restrict__ out) {
  __shared__ short Al[128 * 32];
  __shared__ short B1l[128 * 32];
  __shared__ short B2l[128 * 32];
  const int K = 512;
  int tid = threadIdx.x, lane = tid & 63, wid = tid >> 6;
  int wr = wid >> 1, wc = wid & 1;
  size_t row0 = (size_t)blockIdx.y * 128;
  int col0 = blockIdx.x * 128;
  int arow = lane >> 2, acol = (lane & 3) << 3;
  const unsigned short* Ag = A + (row0 + wid * 32 + arow) * K + acol;
  const unsigned short* B1g = Bt + ((size_t)(col0 + wid * 32 + arow)) * K + acol;
  const unsigned short* B2g = Bt + ((size_t)(col0 + 4096 + wid * 32 + arow)) * K + acol;
  short* Ald = Al + wid * 1024;
  short* B1d = B1l + wid * 1024;
  short* B2d = B2l + wid * 1024;
  f32x4 acc1[4][4] = {}, acc2[4][4] = {};
  int fr = lane & 15, fk = (lane >> 4) << 3;
  for (int k0 = 0; k0 < K; k0 += 32) {
    __syncthreads();
    gload16(Ag + k0, Ald);
    gload16(Ag + (size_t)16 * K + k0, Ald + 512);
    gload16(B1g + k0, B1d);
    gload16(B1g + (size_t)16 * K + k0, B1d + 512);
    gload16(B2g + k0, B2d);
    gload16(B2g + (size_t)16 * K + k0, B2d + 512);
    __syncthreads();
    bf16x8 af[4], b1f[4], b2f[4];
#pragma unroll
    for (int i = 0; i < 4; ++i) {
      af[i] = *(const bf16x8*)&Al[(wr * 64 + i * 16 + fr) * 32 + fk];
      b1f[i] = *(const bf16x8*)&B1l[(wc * 64 + i * 16 + fr) * 32 + fk];
      b2f[i] = *(const bf16x8*)&B2l[(wc * 64 + i * 16 + fr) * 32 + fk];
    }
#pragma unroll
    for (int i = 0; i < 4; ++i)
#pragma unroll
      for (int j = 0; j < 4; ++j) {
        acc1[i][j] = MFMA(af[i], b1f[j], acc1[i][j]);
        acc2[i][j] = MFMA(af[i], b2f[j], acc2[i][j]);
      }
  }
  int cr = (lane >> 4) << 2, cc = lane & 15;
#pragma unroll
  for (int j = 0; j < 4; ++j) {
    int col = col0 + wc * 64 + j * 16 + cc;
    float bb1 = bias[col], bb2 = bias[col + 4096];
#pragma unroll
    for (int i = 0; i < 4; ++i) {
#pragma unroll
      for (int r = 0; r < 4; ++r) {
        size_t row = row0 + wr * 64 + i * 16 + cr + r;
        float h1 = acc1[i][j][r] + bb1;
        float h2 = acc2[i][j][r] + bb2;
        float u = 0.7978845608028654f * (h1 + 0.044715f * h1 * h1 * h1);
        float e = __expf(2.f * u);
        float th = 1.f - 2.f / (e + 1.f);
        float gv = 0.5f * h1 * (1.f + th) * h2;
        out[row * 4096 + col] = f2bf(gv);
      }
    }
  }
}

// ---------------- flash attention: 32x32x16 MFMA, swapped operands ----------------
#define KIX(r, c) ((r) * 64 + ((c) ^ (((r) & 7) << 3)))

__global__ __launch_bounds__(256, 4) void k_attn(const unsigned short* __restrict__ qkv,
                                                 const unsigned short* __restrict__ vT,
                                                 const int* __restrict__ mask,
                                                 unsigned short* __restrict__ ctx) {
  __shared__ short Kl[64 * 64];
  __shared__ short Vl[64 * 64];
  __shared__ short Ol[4][32 * 64];
  __shared__ float mpen[64];
  __shared__ int mflag;
  int bh = blockIdx.y, b = bh >> 4, h = bh & 15;
  int q0 = blockIdx.x << 7;
  int tid = threadIdx.x, lane = tid & 63, wid = tid >> 6;
  int qi = lane & 31, hi = lane >> 5;
  const unsigned short* qrow =
      qkv + ((size_t)(b * 2048 + q0 + wid * 32 + qi)) * 3072 + h * 64 + hi * 8;
  bf16x8 qa[4];
#pragma unroll
  for (int c = 0; c < 4; ++c) qa[c] = *(const bf16x8*)(qrow + c * 16);
  float m_r = -1e30f, l_r = 0.f;
  f32x16 oacc0 = {}, oacc1 = {};
  int srw = lane >> 3;
  int schx = ((lane & 7) ^ srw) << 3;
  int rb = wid * 16;
  const unsigned short* kgb =
      qkv + ((size_t)(b * 2048 + rb + srw)) * 3072 + 1024 + h * 64 + schx;
  const unsigned short* vgb = vT + ((size_t)(bh * 64 + rb + srw)) * 2048 + schx;
  short* kld = Kl + rb * 64;
  short* vld = Vl + rb * 64;
  const int* mbase = mask + b * 2048;
  const f32x16 zero16 = {};
  int mv = (tid < 64) ? mbase[tid] : 1;
  for (int k0 = 0; k0 < 2048; k0 += 64) {
    __syncthreads();
    gload16(kgb + (size_t)k0 * 3072, kld);
    gload16(kgb + (size_t)(k0 + 8) * 3072, kld + 512);
    gload16(vgb + k0, vld);
    gload16(vgb + (size_t)8 * 2048 + k0, vld + 512);
    if (wid == 0) {
      mpen[lane] = (mv == 0) ? -1e30f : 0.f;
      unsigned long long bal = __ballot(mv == 0);
      if (lane == 0) mflag = (bal != 0ull) ? 1 : 0;
    }
    if (k0 + 64 < 2048) mv = (tid < 64) ? mbase[k0 + 64 + tid] : 1;
    __syncthreads();
#pragma unroll
    for (int kt = 0; kt < 2; ++kt) {
      f32x16 s = zero16;
      __builtin_amdgcn_s_setprio(1);
#pragma unroll
      for (int c = 0; c < 4; ++c) {
        bf16x8 kf = *(const bf16x8*)&Kl[KIX(kt * 32 + qi, c * 16 + hi * 8)];
        s = MFMA32(kf, qa[c], s);
      }
      __builtin_amdgcn_s_setprio(0);
      if (mflag) {
        const f32x4* mp4 = (const f32x4*)mpen;
#pragma unroll
        for (int t = 0; t < 4; ++t) {
          f32x4 pen = mp4[kt * 8 + t * 2 + hi];
#pragma unroll
          for (int r = 0; r < 4; ++r) s[t * 4 + r] += pen[r];
        }
      }
      float t0 = max3f(s[0], s[1], s[2]);
      float t1 = max3f(s[3], s[4], s[5]);
      float t2 = max3f(s[6], s[7], s[8]);
      float t3 = max3f(s[9], s[10], s[11]);
      float t4 = max3f(s[12], s[13], s[14]);
      float t5 = fmaxf(t0, s[15]);
      float pmax = max3f(max3f(t5, t1, t2), t3, t4);
      pmax = fmaxf(pmax, __shfl_xor(pmax, 32));
      if (!__all(pmax - m_r <= 8.f)) {
        float mn = fmaxf(m_r, pmax);
        float fac = exp2f(m_r - mn);
        m_r = mn;
        l_r *= fac;
#pragma unroll
        for (int r = 0; r < 16; ++r) { oacc0[r] *= fac; oacc1[r] *= fac; }
      }
#pragma unroll
      for (int r = 0; r < 16; ++r) s[r] = exp2f(s[r] - m_r);
      float su0 = (s[0] + s[1]) + (s[2] + s[3]);
      float su1 = (s[4] + s[5]) + (s[6] + s[7]);
      float su2 = (s[8] + s[9]) + (s[10] + s[11]);
      float su3 = (s[12] + s[13]) + (s[14] + s[15]);
      l_r += (su0 + su1) + (su2 + su3);
      unsigned pk[8];
#pragma unroll
      for (int w = 0; w < 8; ++w)
        asm("v_cvt_pk_bf16_f32 %0, %1, %2" : "=v"(pk[w]) : "v"(s[2 * w]), "v"(s[2 * w + 1]));
      unsigned a0 = pk[0], b0 = pk[2];
      unsigned a1 = pk[1], b1 = pk[3];
      unsigned a2 = pk[4], b2 = pk[6];
      unsigned a3 = pk[5], b3 = pk[7];
      asm("v_permlane32_swap_b32 %0, %1" : "+v"(a0), "+v"(b0));
      asm("v_permlane32_swap_b32 %0, %1" : "+v"(a1), "+v"(b1));
      asm("v_permlane32_swap_b32 %0, %1" : "+v"(a2), "+v"(b2));
      asm("v_permlane32_swap_b32 %0, %1" : "+v"(a3), "+v"(b3));
      union { unsigned u[4]; bf16x8 v; } pb0, pb1;
      pb0.u[0] = a0; pb0.u[1] = a1; pb0.u[2] = b0; pb0.u[3] = b1;
      pb1.u[0] = a2; pb1.u[1] = a3; pb1.u[2] = b2; pb1.u[3] = b3;
      __builtin_amdgcn_s_setprio(1);
      {
        bf16x8 vf00 = *(const bf16x8*)&Vl[KIX(qi, kt * 32 + hi * 8)];
        bf16x8 vf01 = *(const bf16x8*)&Vl[KIX(qi, kt * 32 + 16 + hi * 8)];
        oacc0 = MFMA32(vf00, pb0.v, oacc0);
        oacc0 = MFMA32(vf01, pb1.v, oacc0);
        bf16x8 vf10 = *(const bf16x8*)&Vl[KIX(32 + qi, kt * 32 + hi * 8)];
        bf16x8 vf11 = *(const bf16x8*)&Vl[KIX(32 + qi, kt * 32 + 16 + hi * 8)];
        oacc1 = MFMA32(vf10, pb0.v, oacc1);
        oacc1 = MFMA32(vf11, pb1.v, oacc1);
      }
      __builtin_amdgcn_s_setprio(0);
    }
  }
  l_r += __shfl_xor(l_r, 32);
  float invl = 1.f / l_r;
  short* ob = &Ol[wid][0];
  int xsw = (qi & 7) << 3;
#pragma unroll
  for (int t = 0; t < 4; ++t) {
    int d = t * 8 + 4 * hi;
    float a0 = oacc0[4 * t] * invl, a1 = oacc0[4 * t + 1] * invl;
    float a2 = oacc0[4 * t + 2] * invl, a3 = oacc0[4 * t + 3] * invl;
    unsigned w0, w1;
    asm("v_cvt_pk_bf16_f32 %0, %1, %2" : "=v"(w0) : "v"(a0), "v"(a1));
    asm("v_cvt_pk_bf16_f32 %0, %1, %2" : "=v"(w1) : "v"(a2), "v"(a3));
    *(unsigned long long*)&ob[qi * 64 + (d ^ xsw)] =
        ((unsigned long long)w1 << 32) | (unsigned long long)w0;
    float c0 = oacc1[4 * t] * invl, c1 = oacc1[4 * t + 1] * invl;
    float c2 = oacc1[4 * t + 2] * invl, c3 = oacc1[4 * t + 3] * invl;
    unsigned w2, w3;
    asm("v_cvt_pk_bf16_f32 %0, %1, %2" : "=v"(w2) : "v"(c0), "v"(c1));
    asm("v_cvt_pk_bf16_f32 %0, %1, %2" : "=v"(w3) : "v"(c2), "v"(c3));
    *(unsigned long long*)&ob[qi * 64 + ((d + 32) ^ xsw)] =
        ((unsigned long long)w3 << 32) | (unsigned long long)w2;
  }
  __syncthreads();
#pragma unroll
  for (int p = 0; p < 2; ++p) {
    int q = p * 16 + (lane >> 2);
    int qx = (q & 7) << 3;
    unsigned short* dst =
        ctx + ((size_t)(b * 2048 + q0 + wid * 32 + q)) * 1024 + h * 64;
#pragma unroll
    for (int j = 0; j < 2; ++j) {
      int c = (lane & 3) * 8 + j * 32;
      bf16x8 vv = *(const bf16x8*)&ob[q * 64 + (c ^ qx)];
      __builtin_nontemporal_store(vv, (bf16x8*)(dst + c));
    }
  }
}

// ---------------- launch ----------------
extern "C" void kernel_launch(void* const* d_in, const int* in_sizes, int n_in, void* d_out,
                              int out_size, void* d_ws, size_t ws_size, hipStream_t stream) {
  const float* x = (const float*)d_in[0];
  const int* amask = (const int*)d_in[1];
  const float* ln1w = (const float*)d_in[2];
  const float* ln1b = (const float*)d_in[3];
  const float* Uq = (const float*)d_in[4];
  const float* Vq = (const float*)d_in[5];
  const float* bq = (const float*)d_in[6];
  const float* Uk = (const float*)d_in[7];
  const float* Vk = (const float*)d_in[8];
  const float* bk = (const float*)d_in[9];
  const float* Uv = (const float*)d_in[10];
  const float* Vv = (const float*)d_in[11];
  const float* bv = (const float*)d_in[12];
  const float* Wo = (const float*)d_in[13];
  const float* bo = (const float*)d_in[14];
  const float* ln2w = (const float*)d_in[15];
  const float* ln2b = (const float*)d_in[16];
  const float* Uwi = (const float*)d_in[17];
  const float* Vwi = (const float*)d_in[18];
  const float* bwi = (const float*)d_in[19];
  const float* Uwo = (const float*)d_in[20];
  const float* Vwo = (const float*)d_in[21];
  const float* bwo = (const float*)d_in[22];

  char* ws = (char*)d_ws;
  size_t off = 0;
  auto alloc = [&](size_t bytes) {
    void* p = ws + off;
    off += (bytes + 255) & ~(size_t)255;
    return p;
  };
  unsigned short* xn = (unsigned short*)alloc((size_t)8192 * 1024 * 2);   // also xn2
  unsigned short* Ut = (unsigned short*)alloc((size_t)1536 * 1024 * 2);
  unsigned short* Vt = (unsigned short*)alloc((size_t)48 * 2048 * 2);
  unsigned short* Wob = (unsigned short*)alloc((size_t)1024 * 1024 * 2);
  unsigned short* Uwit = (unsigned short*)alloc((size_t)512 * 1024 * 2);
  unsigned short* Vwit = (unsigned short*)alloc((size_t)8192 * 512 * 2);
  unsigned short* Uwot = (unsigned short*)alloc((size_t)512 * 4096 * 2);
  unsigned short* Vwot = (unsigned short*)alloc((size_t)1024 * 512 * 2);
  unsigned short* qkv = (unsigned short*)alloc((size_t)8192 * 3072 * 2);
  unsigned short* ctx = (unsigned short*)alloc((size_t)8192 * 1024 * 2);
  float* x1 = (float*)alloc((size_t)8192 * 1024 * 4);
  unsigned short* hr = (unsigned short*)alloc((size_t)8192 * 512 * 2);
  unsigned short* gr = (unsigned short*)alloc((size_t)8192 * 512 * 2);
  unsigned short* g = qkv;                 // alias: 64MB over qkv+ctx (dead by FFN)
  unsigned short* xn2 = xn;                // alias: xn dead after QKV
  unsigned short* vT = (unsigned short*)x1;  // alias: x1 written only after attn
  if (off > ws_size) return;               // fail clean instead of faulting
  (void)in_sizes; (void)n_in; (void)out_size;

  dim3 tb(32, 8);
  // weight prep (runs every call; deterministic)
  k_build_ut<<<dim3(32, 48), tb, 0, stream>>>(Uq, Uk, Uv, Ut);
  k_build_vt<<<48, 256, 0, stream>>>(Vq, Vk, Vv, Vt);
  k_f2bf<<<4096, 256, 0, stream>>>(Wo, Wob, 1024 * 1024);
  k_transpose_bf16<<<dim3(512 / 32, 1024 / 32), tb, 0, stream>>>(Uwi, Uwit, 1024, 512);
  k_transpose_bf16<<<dim3(8192 / 32, 512 / 32), tb, 0, stream>>>(Vwi, Vwit, 512, 8192);
  k_transpose_bf16<<<dim3(512 / 32, 4096 / 32), tb, 0, stream>>>(Uwo, Uwot, 4096, 512);
  k_transpose_bf16<<<dim3(1024 / 32, 512 / 32), tb, 0, stream>>>(Vwo, Vwot, 512, 1024);

  // block
  k_layernorm<<<2048, 256, 0, stream>>>(x, ln1w, ln1b, xn);
  k_qkv<<<dim3(12, 64), 256, 0, stream>>>(xn, Ut, Vt, bq, bk, bv, qkv, vT);
  k_attn<<<dim3(16, 64), 256, 0, stream>>>(qkv, vT, amask, ctx);
  k_gemm<2><<<dim3(8, 64), 256, 0, stream>>>(ctx, Wob, bo, x, x1, 1024, 1024);
  k_layernorm<<<2048, 256, 0, stream>>>(x1, ln2w, ln2b, xn2);
  k_gemm<0><<<dim3(4, 64), 256, 0, stream>>>(xn2, Uwit, nullptr, nullptr, hr, 512, 1024);
  k_gemm_geglu<<<dim3(32, 64), 256, 0, stream>>>(hr, Vwit, bwi, g);
  k_gemm<0><<<dim3(4, 64), 256, 0, stream>>>(g, Uwot, nullptr, nullptr, gr, 512, 4096);
  k_gemm<2><<<dim3(8, 64), 256, 0, stream>>>(gr, Vwot, bwo, x1, d_out, 1024, 512);
}

// Round 16
// 474.077 us; speedup vs baseline: 1.0060x; 1.0060x over previous
//
#include <hip/hip_runtime.h>
#include <cstdint>

#define DEV __device__ __forceinline__

typedef __attribute__((ext_vector_type(8))) short bf16x8;
typedef __attribute__((ext_vector_type(4))) float f32x4;
typedef __attribute__((ext_vector_type(16))) float f32x16;

#define MFMA(a,b,c) __builtin_amdgcn_mfma_f32_16x16x32_bf16((a),(b),(c),0,0,0)
#define MFMA32(a,b,c) __builtin_amdgcn_mfma_f32_32x32x16_bf16((a),(b),(c),0,0,0)

DEV unsigned short f2bf(float f) {
  union { float f; unsigned u; } v; v.f = f;
  unsigned r = v.u + 0x7fffu + ((v.u >> 16) & 1u);
  return (unsigned short)(r >> 16);
}
DEV float bf2f(unsigned short s) {
  union { unsigned u; float f; } v; v.u = ((unsigned)s) << 16; return v.f;
}
DEV float max3f(float a, float b, float c) { return fmaxf(fmaxf(a, b), c); }

// async global->LDS, 16B per lane. LDS dest is wave-uniform base + lane*16.
DEV void gload16(const unsigned short* g, short* l) {
  __builtin_amdgcn_global_load_lds(
      (const __attribute__((address_space(1))) unsigned*)g,
      (__attribute__((address_space(3))) unsigned*)l, 16, 0, 0);
}

// ---------------- prep kernels ----------------

// Ut[proj*512 + h*32 + r][d] = U_proj[h][d][r]  (bf16, B^T layout for stage-1)
__global__ void k_build_ut(const float* __restrict__ Uq, const float* __restrict__ Uk,
                           const float* __restrict__ Uv, unsigned short* __restrict__ Ut) {
  __shared__ float tile[32][33];
  int s = blockIdx.y;            // 0..47 = proj*16 + h
  int proj = s >> 4, h = s & 15;
  const float* U = (proj == 0) ? Uq : (proj == 1) ? Uk : Uv;
  const float* Us = U + (size_t)h * 1024 * 32;
  int d0 = blockIdx.x * 32;
  int tx = threadIdx.x, ty = threadIdx.y;
#pragma unroll
  for (int i = ty; i < 32; i += 8)
    tile[i][tx] = Us[(size_t)(d0 + i) * 32 + tx];
  __syncthreads();
#pragma unroll
  for (int i = ty; i < 32; i += 8)
    Ut[(size_t)(s * 32 + i) * 1024 + d0 + tx] = f2bf(tile[tx][i]);
}

// Vt[ph][dh][r] = V_proj[h][r][dh]  (bf16 B^T for stage-2), ph = proj*16 + h
__global__ void k_build_vt(const float* __restrict__ Vq, const float* __restrict__ Vk,
                           const float* __restrict__ Vv, unsigned short* __restrict__ Vt) {
  int ph = blockIdx.x;
  int proj = ph >> 4, h = ph & 15;
  const float* V = (proj == 0) ? Vq : (proj == 1) ? Vk : Vv;
  const float* Vs = V + (size_t)h * 2048;
  int t = threadIdx.x;
#pragma unroll
  for (int idx = t; idx < 2048; idx += 256) {
    int dh = idx >> 5, r = idx & 31;
    Vt[(size_t)ph * 2048 + idx] = f2bf(Vs[r * 64 + dh]);
  }
}

__global__ void k_f2bf(const float* __restrict__ in, unsigned short* __restrict__ out, int n) {
  int i = blockIdx.x * 256 + threadIdx.x;
  if (i < n) out[i] = f2bf(in[i]);
}

// fp32 [R][C] -> bf16 [C][R]
__global__ void k_transpose_bf16(const float* __restrict__ in, unsigned short* __restrict__ out,
                                 int R, int C) {
  __shared__ float tile[32][33];
  int c0 = blockIdx.x * 32, r0 = blockIdx.y * 32;
  int tx = threadIdx.x, ty = threadIdx.y;
#pragma unroll
  for (int i = ty; i < 32; i += 8)
    tile[i][tx] = in[(size_t)(r0 + i) * C + c0 + tx];
  __syncthreads();
#pragma unroll
  for (int i = ty; i < 32; i += 8)
    out[(size_t)(c0 + i) * R + r0 + tx] = f2bf(tile[tx][i]);
}

// ---------------- layernorm: one WAVE per row (4 rows/block, no barrier) ----------------
__global__ __launch_bounds__(256) void k_layernorm(const float* __restrict__ x,
                                                   const float* __restrict__ w,
                                                   const float* __restrict__ b,
                                                   unsigned short* __restrict__ out) {
  int lane = threadIdx.x & 63, wid = threadIdx.x >> 6;
  size_t row = (size_t)blockIdx.x * 4 + wid;
  const float4* xr = (const float4*)(x + row * 1024);
  float4 v[4];
  float s = 0.f, s2 = 0.f;
#pragma unroll
  for (int t = 0; t < 4; ++t) {
    v[t] = xr[lane + t * 64];
    s += v[t].x + v[t].y + v[t].z + v[t].w;
    s2 += v[t].x * v[t].x + v[t].y * v[t].y + v[t].z * v[t].z + v[t].w * v[t].w;
  }
#pragma unroll
  for (int o = 1; o < 64; o <<= 1) { s += __shfl_xor(s, o); s2 += __shfl_xor(s2, o); }
  float mean = s * (1.f / 1024.f);
  float var = s2 * (1.f / 1024.f) - mean * mean;
  float inv = rsqrtf(var + 1e-5f);
  unsigned long long* op = (unsigned long long*)(out + row * 1024);
#pragma unroll
  for (int t = 0; t < 4; ++t) {
    float4 wv = ((const float4*)w)[lane + t * 64];
    float4 bv = ((const float4*)b)[lane + t * 64];
    union { unsigned short u[4]; unsigned long long ll; } o;
    o.u[0] = f2bf((v[t].x - mean) * inv * wv.x + bv.x);
    o.u[1] = f2bf((v[t].y - mean) * inv * wv.y + bv.y);
    o.u[2] = f2bf((v[t].z - mean) * inv * wv.z + bv.z);
    o.u[3] = f2bf((v[t].w - mean) * inv * wv.w + bv.w);
    op[lane + t * 64] = o.ll;
  }
}

// ---------------- GEMM (BK=32, BM=128, BN=128): C = A * Bt^T ----------------
// EPI 0: bf16 out;  1: bf16 out + bias;  2: f32 out + bias + resid
template <int EPI>
__global__ __launch_bounds__(256, 4) void k_gemm(const unsigned short* __restrict__ A,
                                                 const unsigned short* __restrict__ Bt,
                                                 const float* __restrict__ bias,
                                                 const float* __restrict__ resid,
                                                 void* __restrict__ outp, int N, int K) {
  __shared__ short Al[128 * 32];
  __shared__ short Bl[128 * 32];
  int tid = threadIdx.x, lane = tid & 63, wid = tid >> 6;
  int wr = wid >> 1, wc = wid & 1;
  size_t row0 = (size_t)blockIdx.y * 128;
  int col0 = blockIdx.x * 128;
  int arow = lane >> 2, acol = (lane & 3) << 3;
  const unsigned short* Ag = A + (row0 + wid * 32 + arow) * K + acol;
  const unsigned short* Bg = Bt + ((size_t)(col0 + wid * 32 + arow)) * K + acol;
  short* Ald = Al + wid * 1024;
  short* Bld = Bl + wid * 1024;
  f32x4 acc[4][4] = {};
  int fr = lane & 15, fk = (lane >> 4) << 3;
  for (int k0 = 0; k0 < K; k0 += 32) {
    __syncthreads();
    gload16(Ag + k0, Ald);
    gload16(Ag + (size_t)16 * K + k0, Ald + 512);
    gload16(Bg + k0, Bld);
    gload16(Bg + (size_t)16 * K + k0, Bld + 512);
    __syncthreads();
    bf16x8 af[4], bfr[4];
#pragma unroll
    for (int i = 0; i < 4; ++i) {
      af[i] = *(const bf16x8*)&Al[(wr * 64 + i * 16 + fr) * 32 + fk];
      bfr[i] = *(const bf16x8*)&Bl[(wc * 64 + i * 16 + fr) * 32 + fk];
    }
#pragma unroll
    for (int i = 0; i < 4; ++i)
#pragma unroll
      for (int j = 0; j < 4; ++j) acc[i][j] = MFMA(af[i], bfr[j], acc[i][j]);
  }
  int cr = (lane >> 4) << 2, cc = lane & 15;
#pragma unroll
  for (int j = 0; j < 4; ++j) {
    int col = col0 + wc * 64 + j * 16 + cc;
    float bb = (EPI >= 1) ? bias[col] : 0.f;
#pragma unroll
    for (int i = 0; i < 4; ++i) {
#pragma unroll
      for (int r = 0; r < 4; ++r) {
        size_t row = row0 + wr * 64 + i * 16 + cr + r;
        float v = acc[i][j][r] + bb;
        if (EPI == 2)
          ((float*)outp)[row * N + col] = v + resid[row * N + col];
        else
          ((unsigned short*)outp)[row * N + col] = f2bf(v);
      }
    }
  }
}

// ---------------- GEMM64 (BK=32, BM=128, BN=64): for N=512 GEMMs ----------------
// Doubles grid parallelism (512 blocks) for the hr/gr GEMMs that were at 1 block/CU.
// 4 waves, each 32 rows x 64 cols: acc[2][4]. A staged 128x32, B staged 64x32.
__global__ __launch_bounds__(256, 4) void k_gemm64(const unsigned short* __restrict__ A,
                                                   const unsigned short* __restrict__ Bt,
                                                   unsigned short* __restrict__ out,
                                                   int N, int K) {
  __shared__ short Al[128 * 32];
  __shared__ short Bl[64 * 32];
  int tid = threadIdx.x, lane = tid & 63, wid = tid >> 6;
  size_t row0 = (size_t)blockIdx.y * 128;
  int col0 = blockIdx.x * 64;
  int arow = lane >> 2, acol = (lane & 3) << 3;
  const unsigned short* Ag = A + (row0 + wid * 32 + arow) * K + acol;
  const unsigned short* Bg = Bt + ((size_t)(col0 + wid * 16 + arow)) * K + acol;
  short* Ald = Al + wid * 1024;
  short* Bld = Bl + wid * 512;
  f32x4 acc[2][4] = {};
  int fr = lane & 15, fk = (lane >> 4) << 3;
  for (int k0 = 0; k0 < K; k0 += 32) {
    __syncthreads();
    gload16(Ag + k0, Ald);
    gload16(Ag + (size_t)16 * K + k0, Ald + 512);
    gload16(Bg + k0, Bld);
    __syncthreads();
    bf16x8 af[2], bfr[4];
#pragma unroll
    for (int i = 0; i < 2; ++i)
      af[i] = *(const bf16x8*)&Al[(wid * 32 + i * 16 + fr) * 32 + fk];
#pragma unroll
    for (int j = 0; j < 4; ++j)
      bfr[j] = *(const bf16x8*)&Bl[(j * 16 + fr) * 32 + fk];
#pragma unroll
    for (int i = 0; i < 2; ++i)
#pragma unroll
      for (int j = 0; j < 4; ++j) acc[i][j] = MFMA(af[i], bfr[j], acc[i][j]);
  }
  int cr = (lane >> 4) << 2, cc = lane & 15;
#pragma unroll
  for (int j = 0; j < 4; ++j) {
    int col = col0 + j * 16 + cc;
#pragma unroll
    for (int i = 0; i < 2; ++i) {
#pragma unroll
      for (int r = 0; r < 4; ++r) {
        size_t row = row0 + wid * 32 + i * 16 + cr + r;
        out[row * N + col] = f2bf(acc[i][j][r]);
      }
    }
  }
}

// ---------------- fused QKV (BK=32 stage-1): xr = xn @ Ut^T, then per-head
// rank-32 expansion + bias + RoPE; V heads written DIRECTLY to vT (transposed).
__global__ __launch_bounds__(256, 2) void k_qkv(const unsigned short* __restrict__ A,
                                                const unsigned short* __restrict__ Ut,
                                                const unsigned short* __restrict__ Vt,
                                                const float* __restrict__ bq,
                                                const float* __restrict__ bk,
                                                const float* __restrict__ bv,
                                                unsigned short* __restrict__ qkv,
                                                unsigned short* __restrict__ vT) {
  __shared__ short Al[128 * 32];
  __shared__ short Bl[128 * 32];
  __shared__ short Xr[4][64 * 72];
  const int K = 1024, N3 = 3072;
  int tid = threadIdx.x, lane = tid & 63, wid = tid >> 6;
  int wr = wid >> 1, wc = wid & 1;
  size_t row0 = (size_t)blockIdx.y * 128;
  int col0 = blockIdx.x * 128;
  int arow = lane >> 2, acol = (lane & 3) << 3;
  const unsigned short* Ag = A + (row0 + wid * 32 + arow) * K + acol;
  const unsigned short* Bg = Ut + ((size_t)(col0 + wid * 32 + arow)) * K + acol;
  short* Ald = Al + wid * 1024;
  short* Bld = Bl + wid * 1024;
  f32x4 acc[4][4] = {};
  int fr = lane & 15, fk = (lane >> 4) << 3;
  for (int k0 = 0; k0 < K; k0 += 32) {
    __syncthreads();
    gload16(Ag + k0, Ald);
    gload16(Ag + (size_t)16 * K + k0, Ald + 512);
    gload16(Bg + k0, Bld);
    gload16(Bg + (size_t)16 * K + k0, Bld + 512);
    __syncthreads();
    bf16x8 af[4], bfr[4];
#pragma unroll
    for (int i = 0; i < 4; ++i) {
      af[i] = *(const bf16x8*)&Al[(wr * 64 + i * 16 + fr) * 32 + fk];
      bfr[i] = *(const bf16x8*)&Bl[(wc * 64 + i * 16 + fr) * 32 + fk];
    }
#pragma unroll
    for (int i = 0; i < 4; ++i)
#pragma unroll
      for (int j = 0; j < 4; ++j) acc[i][j] = MFMA(af[i], bfr[j], acc[i][j]);
  }
  int cr = (lane >> 4) << 2, cc = lane & 15;
  // bounce xr quadrant (bf16) into per-wave LDS [64 rows][72 cols]
  short* xw = &Xr[wid][0];
#pragma unroll
  for (int j = 0; j < 4; ++j)
#pragma unroll
    for (int i = 0; i < 4; ++i)
#pragma unroll
      for (int r = 0; r < 4; ++r)
        xw[(i * 16 + cr + r) * 72 + j * 16 + cc] = (short)f2bf(acc[i][j][r]);
  // same-wave write->read; compiler inserts lgkmcnt ordering
  int phbase = blockIdx.x * 4 + wc * 2;
  const f32x4 zero4 = {0.f, 0.f, 0.f, 0.f};
#pragma unroll
  for (int h2 = 0; h2 < 2; ++h2) {
    int ph = phbase + h2;
    int proj = ph >> 4, hh = ph & 15;
    bf16x8 af2[4], bf2[4];
#pragma unroll
    for (int i2 = 0; i2 < 4; ++i2)
      af2[i2] = *(const bf16x8*)&xw[(i2 * 16 + fr) * 72 + h2 * 32 + fk];
#pragma unroll
    for (int j2 = 0; j2 < 4; ++j2)
      bf2[j2] = *(const bf16x8*)(Vt + ((size_t)ph * 64 + j2 * 16 + fr) * 32 + fk);
    f32x4 a2[4][4];
#pragma unroll
    for (int i2 = 0; i2 < 4; ++i2)
#pragma unroll
      for (int j2 = 0; j2 < 4; ++j2) a2[i2][j2] = MFMA(af2[i2], bf2[j2], zero4);
    const float* bp = (proj == 0) ? bq : (proj == 1) ? bk : bv;
    if (proj == 2) {  // V: bias + DIRECT transposed write to vT[bh][dh][tok]
      int bq_ = (int)(row0 >> 11);
      int tok0 = (int)(row0 & 2047) + wr * 64;
      unsigned short* vtb = vT + ((size_t)(bq_ * 16 + hh) * 64) * 2048;
#pragma unroll
      for (int j2 = 0; j2 < 4; ++j2) {
        int dh = j2 * 16 + cc;
        float bb = bp[hh * 64 + dh];
        unsigned short* vrow = vtb + (size_t)dh * 2048;
#pragma unroll
        for (int i2 = 0; i2 < 4; ++i2) {
          union { unsigned short u[4]; unsigned long long ll; } o;
#pragma unroll
          for (int r = 0; r < 4; ++r) o.u[r] = f2bf(a2[i2][j2][r] + bb);
          *(unsigned long long*)(vrow + tok0 + i2 * 16 + cr) = o.ll;
        }
      }
    } else {  // Q/K: rotate pairs (dh, dh+32); Q folds 0.125*log2(e)
      int obase = proj * 1024 + hh * 64;
      float sc = (proj == 0) ? 0.18033688011112042f : 1.f;
#pragma unroll
      for (int j2 = 0; j2 < 2; ++j2) {
        int irot = j2 * 16 + cc;  // 0..31
        float freq = __expf((float)irot * -0.28782313662425575f);  // ln(1e4)/32
        float bb1 = bp[hh * 64 + irot];
        float bb2 = bp[hh * 64 + irot + 32];
#pragma unroll
        for (int i2 = 0; i2 < 4; ++i2)
#pragma unroll
          for (int r = 0; r < 4; ++r) {
            size_t row = row0 + wr * 64 + i2 * 16 + cr + r;
            int m = (int)(row & 2047);
            float x1v = a2[i2][j2][r] + bb1;
            float x2v = a2[i2][j2 + 2][r] + bb2;
            float sn, csn;
            __sincosf((float)m * freq, &sn, &csn);
            qkv[row * N3 + obase + irot] = f2bf((x1v * csn - x2v * sn) * sc);
            qkv[row * N3 + obase + irot + 32] = f2bf((x2v * csn + x1v * sn) * sc);
          }
      }
    }
  }
}

// ---------------- GEMM + GEGLU (BK=32): g = gelu_tanh(h1) * h2 ----------------
__global__ __launch_bounds__(256, 2) void k_gemm_geglu(const unsigned short* __restrict__ A,
                                                       const unsigned short* __restrict__ Bt,
                                                       const float* __restrict__ bias,
                                                       unsigned short* __restrict__ out) {
  __shared__ short Al[128 * 32];
  __shared__ short B1l[128 * 32];
  __shared__ short B2l[128 * 32];
  const int K = 512;
  int tid = threadIdx.x, lane = tid & 63, wid = tid >> 6;
  int wr = wid >> 1, wc = wid & 1;
  size_t row0 = (size_t)blockIdx.y * 128;
  int col0 = blockIdx.x * 128;
  int arow = lane >> 2, acol = (lane & 3) << 3;
  const unsigned short* Ag = A + (row0 + wid * 32 + arow) * K + acol;
  const unsigned short* B1g = Bt + ((size_t)(col0 + wid * 32 + arow)) * K + acol;
  const unsigned short* B2g = Bt + ((size_t)(col0 + 4096 + wid * 32 + arow)) * K + acol;
  short* Ald = Al + wid * 1024;
  short* B1d = B1l + wid * 1024;
  short* B2d = B2l + wid * 1024;
  f32x4 acc1[4][4] = {}, acc2[4][4] = {};
  int fr = lane & 15, fk = (lane >> 4) << 3;
  for (int k0 = 0; k0 < K; k0 += 32) {
    __syncthreads();
    gload16(Ag + k0, Ald);
    gload16(Ag + (size_t)16 * K + k0, Ald + 512);
    gload16(B1g + k0, B1d);
    gload16(B1g + (size_t)16 * K + k0, B1d + 512);
    gload16(B2g + k0, B2d);
    gload16(B2g + (size_t)16 * K + k0, B2d + 512);
    __syncthreads();
    bf16x8 af[4], b1f[4], b2f[4];
#pragma unroll
    for (int i = 0; i < 4; ++i) {
      af[i] = *(const bf16x8*)&Al[(wr * 64 + i * 16 + fr) * 32 + fk];
      b1f[i] = *(const bf16x8*)&B1l[(wc * 64 + i * 16 + fr) * 32 + fk];
      b2f[i] = *(const bf16x8*)&B2l[(wc * 64 + i * 16 + fr) * 32 + fk];
    }
#pragma unroll
    for (int i = 0; i < 4; ++i)
#pragma unroll
      for (int j = 0; j < 4; ++j) {
        acc1[i][j] = MFMA(af[i], b1f[j], acc1[i][j]);
        acc2[i][j] = MFMA(af[i], b2f[j], acc2[i][j]);
      }
  }
  int cr = (lane >> 4) << 2, cc = lane & 15;
#pragma unroll
  for (int j = 0; j < 4; ++j) {
    int col = col0 + wc * 64 + j * 16 + cc;
    float bb1 = bias[col], bb2 = bias[col + 4096];
#pragma unroll
    for (int i = 0; i < 4; ++i) {
#pragma unroll
      for (int r = 0; r < 4; ++r) {
        size_t row = row0 + wr * 64 + i * 16 + cr + r;
        float h1 = acc1[i][j][r] + bb1;
        float h2 = acc2[i][j][r] + bb2;
        float u = 0.7978845608028654f * (h1 + 0.044715f * h1 * h1 * h1);
        float e = __expf(2.f * u);
        float th = 1.f - 2.f / (e + 1.f);
        float gv = 0.5f * h1 * (1.f + th) * h2;
        out[row * 4096 + col] = f2bf(gv);
      }
    }
  }
}

// ---------------- flash attention: 32x32x16 MFMA, swapped operands ----------------
#define KIX(r, c) ((r) * 64 + ((c) ^ (((r) & 7) << 3)))

__global__ __launch_bounds__(256, 4) void k_attn(const unsigned short* __restrict__ qkv,
                                                 const unsigned short* __restrict__ vT,
                                                 const int* __restrict__ mask,
                                                 unsigned short* __restrict__ ctx) {
  __shared__ short Kl[64 * 64];
  __shared__ short Vl[64 * 64];
  __shared__ short Ol[4][32 * 64];
  __shared__ float mpen[64];
  __shared__ int mflag;
  int bh = blockIdx.y, b = bh >> 4, h = bh & 15;
  int q0 = blockIdx.x << 7;
  int tid = threadIdx.x, lane = tid & 63, wid = tid >> 6;
  int qi = lane & 31, hi = lane >> 5;
  const unsigned short* qrow =
      qkv + ((size_t)(b * 2048 + q0 + wid * 32 + qi)) * 3072 + h * 64 + hi * 8;
  bf16x8 qa[4];
#pragma unroll
  for (int c = 0; c < 4; ++c) qa[c] = *(const bf16x8*)(qrow + c * 16);
  float m_r = -1e30f, l_r = 0.f;
  f32x16 oacc0 = {}, oacc1 = {};
  int srw = lane >> 3;
  int schx = ((lane & 7) ^ srw) << 3;
  int rb = wid * 16;
  const unsigned short* kgb =
      qkv + ((size_t)(b * 2048 + rb + srw)) * 3072 + 1024 + h * 64 + schx;
  const unsigned short* vgb = vT + ((size_t)(bh * 64 + rb + srw)) * 2048 + schx;
  short* kld = Kl + rb * 64;
  short* vld = Vl + rb * 64;
  const int* mbase = mask + b * 2048;
  const f32x16 zero16 = {};
  int mv = (tid < 64) ? mbase[tid] : 1;
  for (int k0 = 0; k0 < 2048; k0 += 64) {
    __syncthreads();
    gload16(kgb + (size_t)k0 * 3072, kld);
    gload16(kgb + (size_t)(k0 + 8) * 3072, kld + 512);
    gload16(vgb + k0, vld);
    gload16(vgb + (size_t)8 * 2048 + k0, vld + 512);
    if (wid == 0) {
      mpen[lane] = (mv == 0) ? -1e30f : 0.f;
      unsigned long long bal = __ballot(mv == 0);
      if (lane == 0) mflag = (bal != 0ull) ? 1 : 0;
    }
    if (k0 + 64 < 2048) mv = (tid < 64) ? mbase[k0 + 64 + tid] : 1;
    __syncthreads();
#pragma unroll
    for (int kt = 0; kt < 2; ++kt) {
      f32x16 s = zero16;
      __builtin_amdgcn_s_setprio(1);
#pragma unroll
      for (int c = 0; c < 4; ++c) {
        bf16x8 kf = *(const bf16x8*)&Kl[KIX(kt * 32 + qi, c * 16 + hi * 8)];
        s = MFMA32(kf, qa[c], s);
      }
      __builtin_amdgcn_s_setprio(0);
      if (mflag) {
        const f32x4* mp4 = (const f32x4*)mpen;
#pragma unroll
        for (int t = 0; t < 4; ++t) {
          f32x4 pen = mp4[kt * 8 + t * 2 + hi];
#pragma unroll
          for (int r = 0; r < 4; ++r) s[t * 4 + r] += pen[r];
        }
      }
      float t0 = max3f(s[0], s[1], s[2]);
      float t1 = max3f(s[3], s[4], s[5]);
      float t2 = max3f(s[6], s[7], s[8]);
      float t3 = max3f(s[9], s[10], s[11]);
      float t4 = max3f(s[12], s[13], s[14]);
      float t5 = fmaxf(t0, s[15]);
      float pmax = max3f(max3f(t5, t1, t2), t3, t4);
      pmax = fmaxf(pmax, __shfl_xor(pmax, 32));
      if (!__all(pmax - m_r <= 8.f)) {
        float mn = fmaxf(m_r, pmax);
        float fac = exp2f(m_r - mn);
        m_r = mn;
        l_r *= fac;
#pragma unroll
        for (int r = 0; r < 16; ++r) { oacc0[r] *= fac; oacc1[r] *= fac; }
      }
#pragma unroll
      for (int r = 0; r < 16; ++r) s[r] = exp2f(s[r] - m_r);
      float su0 = (s[0] + s[1]) + (s[2] + s[3]);
      float su1 = (s[4] + s[5]) + (s[6] + s[7]);
      float su2 = (s[8] + s[9]) + (s[10] + s[11]);
      float su3 = (s[12] + s[13]) + (s[14] + s[15]);
      l_r += (su0 + su1) + (su2 + su3);
      unsigned pk[8];
#pragma unroll
      for (int w = 0; w < 8; ++w)
        asm("v_cvt_pk_bf16_f32 %0, %1, %2" : "=v"(pk[w]) : "v"(s[2 * w]), "v"(s[2 * w + 1]));
      unsigned a0 = pk[0], b0 = pk[2];
      unsigned a1 = pk[1], b1 = pk[3];
      unsigned a2 = pk[4], b2 = pk[6];
      unsigned a3 = pk[5], b3 = pk[7];
      asm("v_permlane32_swap_b32 %0, %1" : "+v"(a0), "+v"(b0));
      asm("v_permlane32_swap_b32 %0, %1" : "+v"(a1), "+v"(b1));
      asm("v_permlane32_swap_b32 %0, %1" : "+v"(a2), "+v"(b2));
      asm("v_permlane32_swap_b32 %0, %1" : "+v"(a3), "+v"(b3));
      union { unsigned u[4]; bf16x8 v; } pb0, pb1;
      pb0.u[0] = a0; pb0.u[1] = a1; pb0.u[2] = b0; pb0.u[3] = b1;
      pb1.u[0] = a2; pb1.u[1] = a3; pb1.u[2] = b2; pb1.u[3] = b3;
      __builtin_amdgcn_s_setprio(1);
      {
        bf16x8 vf00 = *(const bf16x8*)&Vl[KIX(qi, kt * 32 + hi * 8)];
        bf16x8 vf01 = *(const bf16x8*)&Vl[KIX(qi, kt * 32 + 16 + hi * 8)];
        oacc0 = MFMA32(vf00, pb0.v, oacc0);
        oacc0 = MFMA32(vf01, pb1.v, oacc0);
        bf16x8 vf10 = *(const bf16x8*)&Vl[KIX(32 + qi, kt * 32 + hi * 8)];
        bf16x8 vf11 = *(const bf16x8*)&Vl[KIX(32 + qi, kt * 32 + 16 + hi * 8)];
        oacc1 = MFMA32(vf10, pb0.v, oacc1);
        oacc1 = MFMA32(vf11, pb1.v, oacc1);
      }
      __builtin_amdgcn_s_setprio(0);
    }
  }
  l_r += __shfl_xor(l_r, 32);
  float invl = 1.f / l_r;
  short* ob = &Ol[wid][0];
  int xsw = (qi & 7) << 3;
#pragma unroll
  for (int t = 0; t < 4; ++t) {
    int d = t * 8 + 4 * hi;
    float a0 = oacc0[4 * t] * invl, a1 = oacc0[4 * t + 1] * invl;
    float a2 = oacc0[4 * t + 2] * invl, a3 = oacc0[4 * t + 3] * invl;
    unsigned w0, w1;
    asm("v_cvt_pk_bf16_f32 %0, %1, %2" : "=v"(w0) : "v"(a0), "v"(a1));
    asm("v_cvt_pk_bf16_f32 %0, %1, %2" : "=v"(w1) : "v"(a2), "v"(a3));
    *(unsigned long long*)&ob[qi * 64 + (d ^ xsw)] =
        ((unsigned long long)w1 << 32) | (unsigned long long)w0;
    float c0 = oacc1[4 * t] * invl, c1 = oacc1[4 * t + 1] * invl;
    float c2 = oacc1[4 * t + 2] * invl, c3 = oacc1[4 * t + 3] * invl;
    unsigned w2, w3;
    asm("v_cvt_pk_bf16_f32 %0, %1, %2" : "=v"(w2) : "v"(c0), "v"(c1));
    asm("v_cvt_pk_bf16_f32 %0, %1, %2" : "=v"(w3) : "v"(c2), "v"(c3));
    *(unsigned long long*)&ob[qi * 64 + ((d + 32) ^ xsw)] =
        ((unsigned long long)w3 << 32) | (unsigned long long)w2;
  }
  __syncthreads();
#pragma unroll
  for (int p = 0; p < 2; ++p) {
    int q = p * 16 + (lane >> 2);
    int qx = (q & 7) << 3;
    unsigned short* dst =
        ctx + ((size_t)(b * 2048 + q0 + wid * 32 + q)) * 1024 + h * 64;
#pragma unroll
    for (int j = 0; j < 2; ++j) {
      int c = (lane & 3) * 8 + j * 32;
      bf16x8 vv = *(const bf16x8*)&ob[q * 64 + (c ^ qx)];
      __builtin_nontemporal_store(vv, (bf16x8*)(dst + c));
    }
  }
}

// ---------------- launch ----------------
extern "C" void kernel_launch(void* const* d_in, const int* in_sizes, int n_in, void* d_out,
                              int out_size, void* d_ws, size_t ws_size, hipStream_t stream) {
  const float* x = (const float*)d_in[0];
  const int* amask = (const int*)d_in[1];
  const float* ln1w = (const float*)d_in[2];
  const float* ln1b = (const float*)d_in[3];
  const float* Uq = (const float*)d_in[4];
  const float* Vq = (const float*)d_in[5];
  const float* bq = (const float*)d_in[6];
  const float* Uk = (const float*)d_in[7];
  const float* Vk = (const float*)d_in[8];
  const float* bk = (const float*)d_in[9];
  const float* Uv = (const float*)d_in[10];
  const float* Vv = (const float*)d_in[11];
  const float* bv = (const float*)d_in[12];
  const float* Wo = (const float*)d_in[13];
  const float* bo = (const float*)d_in[14];
  const float* ln2w = (const float*)d_in[15];
  const float* ln2b = (const float*)d_in[16];
  const float* Uwi = (const float*)d_in[17];
  const float* Vwi = (const float*)d_in[18];
  const float* bwi = (const float*)d_in[19];
  const float* Uwo = (const float*)d_in[20];
  const float* Vwo = (const float*)d_in[21];
  const float* bwo = (const float*)d_in[22];

  char* ws = (char*)d_ws;
  size_t off = 0;
  auto alloc = [&](size_t bytes) {
    void* p = ws + off;
    off += (bytes + 255) & ~(size_t)255;
    return p;
  };
  unsigned short* xn = (unsigned short*)alloc((size_t)8192 * 1024 * 2);   // also xn2
  unsigned short* Ut = (unsigned short*)alloc((size_t)1536 * 1024 * 2);
  unsigned short* Vt = (unsigned short*)alloc((size_t)48 * 2048 * 2);
  unsigned short* Wob = (unsigned short*)alloc((size_t)1024 * 1024 * 2);
  unsigned short* Uwit = (unsigned short*)alloc((size_t)512 * 1024 * 2);
  unsigned short* Vwit = (unsigned short*)alloc((size_t)8192 * 512 * 2);
  unsigned short* Uwot = (unsigned short*)alloc((size_t)512 * 4096 * 2);
  unsigned short* Vwot = (unsigned short*)alloc((size_t)1024 * 512 * 2);
  unsigned short* qkv = (unsigned short*)alloc((size_t)8192 * 3072 * 2);
  unsigned short* ctx = (unsigned short*)alloc((size_t)8192 * 1024 * 2);
  float* x1 = (float*)alloc((size_t)8192 * 1024 * 4);
  unsigned short* hr = (unsigned short*)alloc((size_t)8192 * 512 * 2);
  unsigned short* gr = (unsigned short*)alloc((size_t)8192 * 512 * 2);
  unsigned short* g = qkv;                 // alias: 64MB over qkv+ctx (dead by FFN)
  unsigned short* xn2 = xn;                // alias: xn dead after QKV
  unsigned short* vT = (unsigned short*)x1;  // alias: x1 written only after attn
  if (off > ws_size) return;               // fail clean instead of faulting
  (void)in_sizes; (void)n_in; (void)out_size;

  dim3 tb(32, 8);
  // weight prep (runs every call; deterministic)
  k_build_ut<<<dim3(32, 48), tb, 0, stream>>>(Uq, Uk, Uv, Ut);
  k_build_vt<<<48, 256, 0, stream>>>(Vq, Vk, Vv, Vt);
  k_f2bf<<<4096, 256, 0, stream>>>(Wo, Wob, 1024 * 1024);
  k_transpose_bf16<<<dim3(512 / 32, 1024 / 32), tb, 0, stream>>>(Uwi, Uwit, 1024, 512);
  k_transpose_bf16<<<dim3(8192 / 32, 512 / 32), tb, 0, stream>>>(Vwi, Vwit, 512, 8192);
  k_transpose_bf16<<<dim3(512 / 32, 4096 / 32), tb, 0, stream>>>(Uwo, Uwot, 4096, 512);
  k_transpose_bf16<<<dim3(1024 / 32, 512 / 32), tb, 0, stream>>>(Vwo, Vwot, 512, 1024);

  // block
  k_layernorm<<<2048, 256, 0, stream>>>(x, ln1w, ln1b, xn);
  k_qkv<<<dim3(12, 64), 256, 0, stream>>>(xn, Ut, Vt, bq, bk, bv, qkv, vT);
  k_attn<<<dim3(16, 64), 256, 0, stream>>>(qkv, vT, amask, ctx);
  k_gemm<2><<<dim3(8, 64), 256, 0, stream>>>(ctx, Wob, bo, x, x1, 1024, 1024);
  k_layernorm<<<2048, 256, 0, stream>>>(x1, ln2w, ln2b, xn2);
  k_gemm64<<<dim3(8, 64), 256, 0, stream>>>(xn2, Uwit, hr, 512, 1024);
  k_gemm_geglu<<<dim3(32, 64), 256, 0, stream>>>(hr, Vwit, bwi, g);
  k_gemm64<<<dim3(8, 64), 256, 0, stream>>>(g, Uwot, gr, 512, 4096);
  k_gemm<2><<<dim3(8, 64), 256, 0, stream>>>(gr, Vwot, bwo, x1, d_out, 1024, 512);
}

// Round 17
// 472.095 us; speedup vs baseline: 1.0103x; 1.0042x over previous
//
#include <hip/hip_runtime.h>
#include <cstdint>

#define DEV __device__ __forceinline__

typedef __attribute__((ext_vector_type(8))) short bf16x8;
typedef __attribute__((ext_vector_type(4))) float f32x4;
typedef __attribute__((ext_vector_type(16))) float f32x16;

#define MFMA(a,b,c) __builtin_amdgcn_mfma_f32_16x16x32_bf16((a),(b),(c),0,0,0)
#define MFMA32(a,b,c) __builtin_amdgcn_mfma_f32_32x32x16_bf16((a),(b),(c),0,0,0)

DEV unsigned short f2bf(float f) {
  union { float f; unsigned u; } v; v.f = f;
  unsigned r = v.u + 0x7fffu + ((v.u >> 16) & 1u);
  return (unsigned short)(r >> 16);
}
DEV float bf2f(unsigned short s) {
  union { unsigned u; float f; } v; v.u = ((unsigned)s) << 16; return v.f;
}
DEV float max3f(float a, float b, float c) { return fmaxf(fmaxf(a, b), c); }

// async global->LDS, 16B per lane. LDS dest is wave-uniform base + lane*16.
DEV void gload16(const unsigned short* g, short* l) {
  __builtin_amdgcn_global_load_lds(
      (const __attribute__((address_space(1))) unsigned*)g,
      (__attribute__((address_space(3))) unsigned*)l, 16, 0, 0);
}

// ---------------- prep kernels ----------------

// Ut[proj*512 + h*32 + r][d] = U_proj[h][d][r]  (bf16, B^T layout for stage-1)
__global__ void k_build_ut(const float* __restrict__ Uq, const float* __restrict__ Uk,
                           const float* __restrict__ Uv, unsigned short* __restrict__ Ut) {
  __shared__ float tile[32][33];
  int s = blockIdx.y;            // 0..47 = proj*16 + h
  int proj = s >> 4, h = s & 15;
  const float* U = (proj == 0) ? Uq : (proj == 1) ? Uk : Uv;
  const float* Us = U + (size_t)h * 1024 * 32;
  int d0 = blockIdx.x * 32;
  int tx = threadIdx.x, ty = threadIdx.y;
#pragma unroll
  for (int i = ty; i < 32; i += 8)
    tile[i][tx] = Us[(size_t)(d0 + i) * 32 + tx];
  __syncthreads();
#pragma unroll
  for (int i = ty; i < 32; i += 8)
    Ut[(size_t)(s * 32 + i) * 1024 + d0 + tx] = f2bf(tile[tx][i]);
}

// Vt[ph][dh][r] = V_proj[h][r][dh]  (bf16 B^T for stage-2), ph = proj*16 + h
__global__ void k_build_vt(const float* __restrict__ Vq, const float* __restrict__ Vk,
                           const float* __restrict__ Vv, unsigned short* __restrict__ Vt) {
  int ph = blockIdx.x;
  int proj = ph >> 4, h = ph & 15;
  const float* V = (proj == 0) ? Vq : (proj == 1) ? Vk : Vv;
  const float* Vs = V + (size_t)h * 2048;
  int t = threadIdx.x;
#pragma unroll
  for (int idx = t; idx < 2048; idx += 256) {
    int dh = idx >> 5, r = idx & 31;
    Vt[(size_t)ph * 2048 + idx] = f2bf(Vs[r * 64 + dh]);
  }
}

__global__ void k_f2bf(const float* __restrict__ in, unsigned short* __restrict__ out, int n) {
  int i = blockIdx.x * 256 + threadIdx.x;
  if (i < n) out[i] = f2bf(in[i]);
}

// fp32 [R][C] -> bf16 [C][R]
__global__ void k_transpose_bf16(const float* __restrict__ in, unsigned short* __restrict__ out,
                                 int R, int C) {
  __shared__ float tile[32][33];
  int c0 = blockIdx.x * 32, r0 = blockIdx.y * 32;
  int tx = threadIdx.x, ty = threadIdx.y;
#pragma unroll
  for (int i = ty; i < 32; i += 8)
    tile[i][tx] = in[(size_t)(r0 + i) * C + c0 + tx];
  __syncthreads();
#pragma unroll
  for (int i = ty; i < 32; i += 8)
    out[(size_t)(c0 + i) * R + r0 + tx] = f2bf(tile[tx][i]);
}

// ---------------- layernorm: one WAVE per row (4 rows/block, no barrier) ----------------
__global__ __launch_bounds__(256) void k_layernorm(const float* __restrict__ x,
                                                   const float* __restrict__ w,
                                                   const float* __restrict__ b,
                                                   unsigned short* __restrict__ out) {
  int lane = threadIdx.x & 63, wid = threadIdx.x >> 6;
  size_t row = (size_t)blockIdx.x * 4 + wid;
  const float4* xr = (const float4*)(x + row * 1024);
  float4 v[4];
  float s = 0.f, s2 = 0.f;
#pragma unroll
  for (int t = 0; t < 4; ++t) {
    v[t] = xr[lane + t * 64];
    s += v[t].x + v[t].y + v[t].z + v[t].w;
    s2 += v[t].x * v[t].x + v[t].y * v[t].y + v[t].z * v[t].z + v[t].w * v[t].w;
  }
#pragma unroll
  for (int o = 1; o < 64; o <<= 1) { s += __shfl_xor(s, o); s2 += __shfl_xor(s2, o); }
  float mean = s * (1.f / 1024.f);
  float var = s2 * (1.f / 1024.f) - mean * mean;
  float inv = rsqrtf(var + 1e-5f);
  unsigned long long* op = (unsigned long long*)(out + row * 1024);
#pragma unroll
  for (int t = 0; t < 4; ++t) {
    float4 wv = ((const float4*)w)[lane + t * 64];
    float4 bv = ((const float4*)b)[lane + t * 64];
    union { unsigned short u[4]; unsigned long long ll; } o;
    o.u[0] = f2bf((v[t].x - mean) * inv * wv.x + bv.x);
    o.u[1] = f2bf((v[t].y - mean) * inv * wv.y + bv.y);
    o.u[2] = f2bf((v[t].z - mean) * inv * wv.z + bv.z);
    o.u[3] = f2bf((v[t].w - mean) * inv * wv.w + bv.w);
    op[lane + t * 64] = o.ll;
  }
}

// ---------------- GEMM (BK=32, BM=128, BN=128): C = A * Bt^T ----------------
// EPI 0: bf16 out;  1: bf16 out + bias;  2: f32 out + bias + resid
template <int EPI>
__global__ __launch_bounds__(256, 4) void k_gemm(const unsigned short* __restrict__ A,
                                                 const unsigned short* __restrict__ Bt,
                                                 const float* __restrict__ bias,
                                                 const float* __restrict__ resid,
                                                 void* __restrict__ outp, int N, int K) {
  __shared__ short Al[128 * 32];
  __shared__ short Bl[128 * 32];
  int tid = threadIdx.x, lane = tid & 63, wid = tid >> 6;
  int wr = wid >> 1, wc = wid & 1;
  size_t row0 = (size_t)blockIdx.y * 128;
  int col0 = blockIdx.x * 128;
  int arow = lane >> 2, acol = (lane & 3) << 3;
  const unsigned short* Ag = A + (row0 + wid * 32 + arow) * K + acol;
  const unsigned short* Bg = Bt + ((size_t)(col0 + wid * 32 + arow)) * K + acol;
  short* Ald = Al + wid * 1024;
  short* Bld = Bl + wid * 1024;
  f32x4 acc[4][4] = {};
  int fr = lane & 15, fk = (lane >> 4) << 3;
  for (int k0 = 0; k0 < K; k0 += 32) {
    __syncthreads();
    gload16(Ag + k0, Ald);
    gload16(Ag + (size_t)16 * K + k0, Ald + 512);
    gload16(Bg + k0, Bld);
    gload16(Bg + (size_t)16 * K + k0, Bld + 512);
    __syncthreads();
    bf16x8 af[4], bfr[4];
#pragma unroll
    for (int i = 0; i < 4; ++i) {
      af[i] = *(const bf16x8*)&Al[(wr * 64 + i * 16 + fr) * 32 + fk];
      bfr[i] = *(const bf16x8*)&Bl[(wc * 64 + i * 16 + fr) * 32 + fk];
    }
#pragma unroll
    for (int i = 0; i < 4; ++i)
#pragma unroll
      for (int j = 0; j < 4; ++j) acc[i][j] = MFMA(af[i], bfr[j], acc[i][j]);
  }
  int cr = (lane >> 4) << 2, cc = lane & 15;
#pragma unroll
  for (int j = 0; j < 4; ++j) {
    int col = col0 + wc * 64 + j * 16 + cc;
    float bb = (EPI >= 1) ? bias[col] : 0.f;
#pragma unroll
    for (int i = 0; i < 4; ++i) {
#pragma unroll
      for (int r = 0; r < 4; ++r) {
        size_t row = row0 + wr * 64 + i * 16 + cr + r;
        float v = acc[i][j][r] + bb;
        if (EPI == 2)
          ((float*)outp)[row * N + col] = v + resid[row * N + col];
        else
          ((unsigned short*)outp)[row * N + col] = f2bf(v);
      }
    }
  }
}

// ---------------- GEMM64 (BK=32, BM=128, BN=64): for N=512 GEMMs ----------------
__global__ __launch_bounds__(256, 4) void k_gemm64(const unsigned short* __restrict__ A,
                                                   const unsigned short* __restrict__ Bt,
                                                   unsigned short* __restrict__ out,
                                                   int N, int K) {
  __shared__ short Al[128 * 32];
  __shared__ short Bl[64 * 32];
  int tid = threadIdx.x, lane = tid & 63, wid = tid >> 6;
  size_t row0 = (size_t)blockIdx.y * 128;
  int col0 = blockIdx.x * 64;
  int arow = lane >> 2, acol = (lane & 3) << 3;
  const unsigned short* Ag = A + (row0 + wid * 32 + arow) * K + acol;
  const unsigned short* Bg = Bt + ((size_t)(col0 + wid * 16 + arow)) * K + acol;
  short* Ald = Al + wid * 1024;
  short* Bld = Bl + wid * 512;
  f32x4 acc[2][4] = {};
  int fr = lane & 15, fk = (lane >> 4) << 3;
  for (int k0 = 0; k0 < K; k0 += 32) {
    __syncthreads();
    gload16(Ag + k0, Ald);
    gload16(Ag + (size_t)16 * K + k0, Ald + 512);
    gload16(Bg + k0, Bld);
    __syncthreads();
    bf16x8 af[2], bfr[4];
#pragma unroll
    for (int i = 0; i < 2; ++i)
      af[i] = *(const bf16x8*)&Al[(wid * 32 + i * 16 + fr) * 32 + fk];
#pragma unroll
    for (int j = 0; j < 4; ++j)
      bfr[j] = *(const bf16x8*)&Bl[(j * 16 + fr) * 32 + fk];
#pragma unroll
    for (int i = 0; i < 2; ++i)
#pragma unroll
      for (int j = 0; j < 4; ++j) acc[i][j] = MFMA(af[i], bfr[j], acc[i][j]);
  }
  int cr = (lane >> 4) << 2, cc = lane & 15;
#pragma unroll
  for (int j = 0; j < 4; ++j) {
    int col = col0 + j * 16 + cc;
#pragma unroll
    for (int i = 0; i < 2; ++i) {
#pragma unroll
      for (int r = 0; r < 4; ++r) {
        size_t row = row0 + wid * 32 + i * 16 + cr + r;
        out[row * N + col] = f2bf(acc[i][j][r]);
      }
    }
  }
}

// ---------------- fused QKV (BK=32 stage-1): xr = xn @ Ut^T, then per-head
// rank-32 expansion + bias + RoPE; V heads written DIRECTLY to vT (transposed).
__global__ __launch_bounds__(256, 2) void k_qkv(const unsigned short* __restrict__ A,
                                                const unsigned short* __restrict__ Ut,
                                                const unsigned short* __restrict__ Vt,
                                                const float* __restrict__ bq,
                                                const float* __restrict__ bk,
                                                const float* __restrict__ bv,
                                                unsigned short* __restrict__ qkv,
                                                unsigned short* __restrict__ vT) {
  __shared__ short Al[128 * 32];
  __shared__ short Bl[128 * 32];
  __shared__ short Xr[4][64 * 72];
  const int K = 1024, N3 = 3072;
  int tid = threadIdx.x, lane = tid & 63, wid = tid >> 6;
  int wr = wid >> 1, wc = wid & 1;
  size_t row0 = (size_t)blockIdx.y * 128;
  int col0 = blockIdx.x * 128;
  int arow = lane >> 2, acol = (lane & 3) << 3;
  const unsigned short* Ag = A + (row0 + wid * 32 + arow) * K + acol;
  const unsigned short* Bg = Ut + ((size_t)(col0 + wid * 32 + arow)) * K + acol;
  short* Ald = Al + wid * 1024;
  short* Bld = Bl + wid * 1024;
  f32x4 acc[4][4] = {};
  int fr = lane & 15, fk = (lane >> 4) << 3;
  for (int k0 = 0; k0 < K; k0 += 32) {
    __syncthreads();
    gload16(Ag + k0, Ald);
    gload16(Ag + (size_t)16 * K + k0, Ald + 512);
    gload16(Bg + k0, Bld);
    gload16(Bg + (size_t)16 * K + k0, Bld + 512);
    __syncthreads();
    bf16x8 af[4], bfr[4];
#pragma unroll
    for (int i = 0; i < 4; ++i) {
      af[i] = *(const bf16x8*)&Al[(wr * 64 + i * 16 + fr) * 32 + fk];
      bfr[i] = *(const bf16x8*)&Bl[(wc * 64 + i * 16 + fr) * 32 + fk];
    }
#pragma unroll
    for (int i = 0; i < 4; ++i)
#pragma unroll
      for (int j = 0; j < 4; ++j) acc[i][j] = MFMA(af[i], bfr[j], acc[i][j]);
  }
  int cr = (lane >> 4) << 2, cc = lane & 15;
  // bounce xr quadrant (bf16) into per-wave LDS [64 rows][72 cols]
  short* xw = &Xr[wid][0];
#pragma unroll
  for (int j = 0; j < 4; ++j)
#pragma unroll
    for (int i = 0; i < 4; ++i)
#pragma unroll
      for (int r = 0; r < 4; ++r)
        xw[(i * 16 + cr + r) * 72 + j * 16 + cc] = (short)f2bf(acc[i][j][r]);
  // same-wave write->read; compiler inserts lgkmcnt ordering
  int phbase = blockIdx.x * 4 + wc * 2;
  const f32x4 zero4 = {0.f, 0.f, 0.f, 0.f};
#pragma unroll
  for (int h2 = 0; h2 < 2; ++h2) {
    int ph = phbase + h2;
    int proj = ph >> 4, hh = ph & 15;
    bf16x8 af2[4], bf2[4];
#pragma unroll
    for (int i2 = 0; i2 < 4; ++i2)
      af2[i2] = *(const bf16x8*)&xw[(i2 * 16 + fr) * 72 + h2 * 32 + fk];
#pragma unroll
    for (int j2 = 0; j2 < 4; ++j2)
      bf2[j2] = *(const bf16x8*)(Vt + ((size_t)ph * 64 + j2 * 16 + fr) * 32 + fk);
    f32x4 a2[4][4];
#pragma unroll
    for (int i2 = 0; i2 < 4; ++i2)
#pragma unroll
      for (int j2 = 0; j2 < 4; ++j2) a2[i2][j2] = MFMA(af2[i2], bf2[j2], zero4);
    const float* bp = (proj == 0) ? bq : (proj == 1) ? bk : bv;
    if (proj == 2) {  // V: bias + DIRECT transposed write to vT[bh][dh][tok]
      int bq_ = (int)(row0 >> 11);
      int tok0 = (int)(row0 & 2047) + wr * 64;
      unsigned short* vtb = vT + ((size_t)(bq_ * 16 + hh) * 64) * 2048;
#pragma unroll
      for (int j2 = 0; j2 < 4; ++j2) {
        int dh = j2 * 16 + cc;
        float bb = bp[hh * 64 + dh];
        unsigned short* vrow = vtb + (size_t)dh * 2048;
#pragma unroll
        for (int i2 = 0; i2 < 4; ++i2) {
          union { unsigned short u[4]; unsigned long long ll; } o;
#pragma unroll
          for (int r = 0; r < 4; ++r) o.u[r] = f2bf(a2[i2][j2][r] + bb);
          *(unsigned long long*)(vrow + tok0 + i2 * 16 + cr) = o.ll;
        }
      }
    } else {  // Q/K: rotate pairs (dh, dh+32); Q folds 0.125*log2(e)
      int obase = proj * 1024 + hh * 64;
      float sc = (proj == 0) ? 0.18033688011112042f : 1.f;
#pragma unroll
      for (int j2 = 0; j2 < 2; ++j2) {
        int irot = j2 * 16 + cc;  // 0..31
        float freq = __expf((float)irot * -0.28782313662425575f);  // ln(1e4)/32
        float bb1 = bp[hh * 64 + irot];
        float bb2 = bp[hh * 64 + irot + 32];
#pragma unroll
        for (int i2 = 0; i2 < 4; ++i2)
#pragma unroll
          for (int r = 0; r < 4; ++r) {
            size_t row = row0 + wr * 64 + i2 * 16 + cr + r;
            int m = (int)(row & 2047);
            float x1v = a2[i2][j2][r] + bb1;
            float x2v = a2[i2][j2 + 2][r] + bb2;
            float sn, csn;
            __sincosf((float)m * freq, &sn, &csn);
            qkv[row * N3 + obase + irot] = f2bf((x1v * csn - x2v * sn) * sc);
            qkv[row * N3 + obase + irot + 32] = f2bf((x2v * csn + x1v * sn) * sc);
          }
      }
    }
  }
}

// ---------------- GEMM + GEGLU (BK=32): g = gelu_tanh(h1) * h2 ----------------
__global__ __launch_bounds__(256, 2) void k_gemm_geglu(const unsigned short* __restrict__ A,
                                                       const unsigned short* __restrict__ Bt,
                                                       const float* __restrict__ bias,
                                                       unsigned short* __restrict__ out) {
  __shared__ short Al[128 * 32];
  __shared__ short B1l[128 * 32];
  __shared__ short B2l[128 * 32];
  const int K = 512;
  int tid = threadIdx.x, lane = tid & 63, wid = tid >> 6;
  int wr = wid >> 1, wc = wid & 1;
  size_t row0 = (size_t)blockIdx.y * 128;
  int col0 = blockIdx.x * 128;
  int arow = lane >> 2, acol = (lane & 3) << 3;
  const unsigned short* Ag = A + (row0 + wid * 32 + arow) * K + acol;
  const unsigned short* B1g = Bt + ((size_t)(col0 + wid * 32 + arow)) * K + acol;
  const unsigned short* B2g = Bt + ((size_t)(col0 + 4096 + wid * 32 + arow)) * K + acol;
  short* Ald = Al + wid * 1024;
  short* B1d = B1l + wid * 1024;
  short* B2d = B2l + wid * 1024;
  f32x4 acc1[4][4] = {}, acc2[4][4] = {};
  int fr = lane & 15, fk = (lane >> 4) << 3;
  for (int k0 = 0; k0 < K; k0 += 32) {
    __syncthreads();
    gload16(Ag + k0, Ald);
    gload16(Ag + (size_t)16 * K + k0, Ald + 512);
    gload16(B1g + k0, B1d);
    gload16(B1g + (size_t)16 * K + k0, B1d + 512);
    gload16(B2g + k0, B2d);
    gload16(B2g + (size_t)16 * K + k0, B2d + 512);
    __syncthreads();
    bf16x8 af[4], b1f[4], b2f[4];
#pragma unroll
    for (int i = 0; i < 4; ++i) {
      af[i] = *(const bf16x8*)&Al[(wr * 64 + i * 16 + fr) * 32 + fk];
      b1f[i] = *(const bf16x8*)&B1l[(wc * 64 + i * 16 + fr) * 32 + fk];
      b2f[i] = *(const bf16x8*)&B2l[(wc * 64 + i * 16 + fr) * 32 + fk];
    }
#pragma unroll
    for (int i = 0; i < 4; ++i)
#pragma unroll
      for (int j = 0; j < 4; ++j) {
        acc1[i][j] = MFMA(af[i], b1f[j], acc1[i][j]);
        acc2[i][j] = MFMA(af[i], b2f[j], acc2[i][j]);
      }
  }
  int cr = (lane >> 4) << 2, cc = lane & 15;
#pragma unroll
  for (int j = 0; j < 4; ++j) {
    int col = col0 + wc * 64 + j * 16 + cc;
    float bb1 = bias[col], bb2 = bias[col + 4096];
#pragma unroll
    for (int i = 0; i < 4; ++i) {
#pragma unroll
      for (int r = 0; r < 4; ++r) {
        size_t row = row0 + wr * 64 + i * 16 + cr + r;
        float h1 = acc1[i][j][r] + bb1;
        float h2 = acc2[i][j][r] + bb2;
        float u = 0.7978845608028654f * (h1 + 0.044715f * h1 * h1 * h1);
        float e = __expf(2.f * u);
        float th = 1.f - 2.f / (e + 1.f);
        float gv = 0.5f * h1 * (1.f + th) * h2;
        out[row * 4096 + col] = f2bf(gv);
      }
    }
  }
}

// ---------------- flash attention: 32x32x16 MFMA, double-buffered K/V ----------------
// T3 minimum 2-phase: one barrier per tile; next tile's gloads issued right after
// the barrier, hidden under QK+softmax+PV. Mask handled via per-wave register
// bitmask (no LDS bounce). O epilogue staging aliases KV buffer 0.
#define KIX(r, c) ((r) * 64 + ((c) ^ (((r) & 7) << 3)))

__global__ __launch_bounds__(256, 4) void k_attn(const unsigned short* __restrict__ qkv,
                                                 const unsigned short* __restrict__ vT,
                                                 const int* __restrict__ mask,
                                                 unsigned short* __restrict__ ctx) {
  __shared__ short pool[16384];  // [buf0: K 4096 | V 4096][buf1: K 4096 | V 4096]
  int bh = blockIdx.y, b = bh >> 4, h = bh & 15;
  int q0 = blockIdx.x << 7;
  int tid = threadIdx.x, lane = tid & 63, wid = tid >> 6;
  int qi = lane & 31, hi = lane >> 5;
  const unsigned short* qrow =
      qkv + ((size_t)(b * 2048 + q0 + wid * 32 + qi)) * 3072 + h * 64 + hi * 8;
  bf16x8 qa[4];
#pragma unroll
  for (int c = 0; c < 4; ++c) qa[c] = *(const bf16x8*)(qrow + c * 16);
  float m_r = -1e30f, l_r = 0.f;
  f32x16 oacc0 = {}, oacc1 = {};
  int srw = lane >> 3;
  int schx = ((lane & 7) ^ srw) << 3;
  int rb = wid * 16;
  const unsigned short* kgb =
      qkv + ((size_t)(b * 2048 + rb + srw)) * 3072 + 1024 + h * 64 + schx;
  const unsigned short* vgb = vT + ((size_t)(bh * 64 + rb + srw)) * 2048 + schx;
  const int* mbase = mask + b * 2048;
  const f32x16 zero16 = {};
  // per-wave mask bitmask: bit t set if tile t has any masked key
  unsigned mbits = 0;
  for (int t = 0; t < 32; ++t) {
    int mv = mbase[t * 64 + lane];
    if (__ballot(mv == 0) != 0ull) mbits |= (1u << t);
  }
  // prologue: stage tile 0 into buf 0
  {
    short* kb0 = pool + rb * 64;
    short* vb0 = pool + 4096 + rb * 64;
    gload16(kgb, kb0);
    gload16(kgb + (size_t)8 * 3072, kb0 + 512);
    gload16(vgb, vb0);
    gload16(vgb + (size_t)8 * 2048, vb0 + 512);
  }
  int cur = 0;
  for (int k0 = 0; k0 < 2048; k0 += 64) {
    __syncthreads();  // drains vmcnt: buf[cur] ready; prior buf[cur^1] reads done
    if (k0 + 64 < 2048) {  // stage next tile into buf[cur^1] (hidden under compute)
      short* kn = pool + (cur ^ 1) * 8192 + rb * 64;
      short* vn = pool + (cur ^ 1) * 8192 + 4096 + rb * 64;
      gload16(kgb + (size_t)(k0 + 64) * 3072, kn);
      gload16(kgb + (size_t)(k0 + 72) * 3072, kn + 512);
      gload16(vgb + (k0 + 64), vn);
      gload16(vgb + (size_t)8 * 2048 + (k0 + 64), vn + 512);
    }
    const short* Kl = pool + cur * 8192;
    const short* Vl = pool + cur * 8192 + 4096;
    bool masked = (mbits >> (k0 >> 6)) & 1;
#pragma unroll
    for (int kt = 0; kt < 2; ++kt) {
      f32x16 s = zero16;
      __builtin_amdgcn_s_setprio(1);
#pragma unroll
      for (int c = 0; c < 4; ++c) {
        bf16x8 kf = *(const bf16x8*)&Kl[KIX(kt * 32 + qi, c * 16 + hi * 8)];
        s = MFMA32(kf, qa[c], s);
      }
      __builtin_amdgcn_s_setprio(0);
      if (masked) {  // rare: load penalties directly (L2-hot 8KB mask)
#pragma unroll
        for (int t = 0; t < 4; ++t) {
          int mi = k0 + kt * 32 + 8 * t + 4 * hi;
#pragma unroll
          for (int r = 0; r < 4; ++r)
            s[t * 4 + r] += (mbase[mi + r] == 0) ? -1e30f : 0.f;
        }
      }
      float t0 = max3f(s[0], s[1], s[2]);
      float t1 = max3f(s[3], s[4], s[5]);
      float t2 = max3f(s[6], s[7], s[8]);
      float t3 = max3f(s[9], s[10], s[11]);
      float t4 = max3f(s[12], s[13], s[14]);
      float t5 = fmaxf(t0, s[15]);
      float pmax = max3f(max3f(t5, t1, t2), t3, t4);
      pmax = fmaxf(pmax, __shfl_xor(pmax, 32));
      if (!__all(pmax - m_r <= 8.f)) {
        float mn = fmaxf(m_r, pmax);
        float fac = exp2f(m_r - mn);
        m_r = mn;
        l_r *= fac;
#pragma unroll
        for (int r = 0; r < 16; ++r) { oacc0[r] *= fac; oacc1[r] *= fac; }
      }
#pragma unroll
      for (int r = 0; r < 16; ++r) s[r] = exp2f(s[r] - m_r);
      float su0 = (s[0] + s[1]) + (s[2] + s[3]);
      float su1 = (s[4] + s[5]) + (s[6] + s[7]);
      float su2 = (s[8] + s[9]) + (s[10] + s[11]);
      float su3 = (s[12] + s[13]) + (s[14] + s[15]);
      l_r += (su0 + su1) + (su2 + su3);
      unsigned pk[8];
#pragma unroll
      for (int w = 0; w < 8; ++w)
        asm("v_cvt_pk_bf16_f32 %0, %1, %2" : "=v"(pk[w]) : "v"(s[2 * w]), "v"(s[2 * w + 1]));
      unsigned a0 = pk[0], b0 = pk[2];
      unsigned a1 = pk[1], b1 = pk[3];
      unsigned a2 = pk[4], b2 = pk[6];
      unsigned a3 = pk[5], b3 = pk[7];
      asm("v_permlane32_swap_b32 %0, %1" : "+v"(a0), "+v"(b0));
      asm("v_permlane32_swap_b32 %0, %1" : "+v"(a1), "+v"(b1));
      asm("v_permlane32_swap_b32 %0, %1" : "+v"(a2), "+v"(b2));
      asm("v_permlane32_swap_b32 %0, %1" : "+v"(a3), "+v"(b3));
      union { unsigned u[4]; bf16x8 v; } pb0, pb1;
      pb0.u[0] = a0; pb0.u[1] = a1; pb0.u[2] = b0; pb0.u[3] = b1;
      pb1.u[0] = a2; pb1.u[1] = a3; pb1.u[2] = b2; pb1.u[3] = b3;
      __builtin_amdgcn_s_setprio(1);
      {
        bf16x8 vf00 = *(const bf16x8*)&Vl[KIX(qi, kt * 32 + hi * 8)];
        bf16x8 vf01 = *(const bf16x8*)&Vl[KIX(qi, kt * 32 + 16 + hi * 8)];
        oacc0 = MFMA32(vf00, pb0.v, oacc0);
        oacc0 = MFMA32(vf01, pb1.v, oacc0);
        bf16x8 vf10 = *(const bf16x8*)&Vl[KIX(32 + qi, kt * 32 + hi * 8)];
        bf16x8 vf11 = *(const bf16x8*)&Vl[KIX(32 + qi, kt * 32 + 16 + hi * 8)];
        oacc1 = MFMA32(vf10, pb0.v, oacc1);
        oacc1 = MFMA32(vf11, pb1.v, oacc1);
      }
      __builtin_amdgcn_s_setprio(0);
    }
    cur ^= 1;
  }
  l_r += __shfl_xor(l_r, 32);
  float invl = 1.f / l_r;
  __syncthreads();  // all KV reads done -> safe to alias buf0 as O staging
  short* ob = pool + wid * 2048;  // [32 q][64 d] per wave
  int xsw = (qi & 7) << 3;
#pragma unroll
  for (int t = 0; t < 4; ++t) {
    int d = t * 8 + 4 * hi;
    float a0 = oacc0[4 * t] * invl, a1 = oacc0[4 * t + 1] * invl;
    float a2 = oacc0[4 * t + 2] * invl, a3 = oacc0[4 * t + 3] * invl;
    unsigned w0, w1;
    asm("v_cvt_pk_bf16_f32 %0, %1, %2" : "=v"(w0) : "v"(a0), "v"(a1));
    asm("v_cvt_pk_bf16_f32 %0, %1, %2" : "=v"(w1) : "v"(a2), "v"(a3));
    *(unsigned long long*)&ob[qi * 64 + (d ^ xsw)] =
        ((unsigned long long)w1 << 32) | (unsigned long long)w0;
    float c0 = oacc1[4 * t] * invl, c1 = oacc1[4 * t + 1] * invl;
    float c2 = oacc1[4 * t + 2] * invl, c3 = oacc1[4 * t + 3] * invl;
    unsigned w2, w3;
    asm("v_cvt_pk_bf16_f32 %0, %1, %2" : "=v"(w2) : "v"(c0), "v"(c1));
    asm("v_cvt_pk_bf16_f32 %0, %1, %2" : "=v"(w3) : "v"(c2), "v"(c3));
    *(unsigned long long*)&ob[qi * 64 + ((d + 32) ^ xsw)] =
        ((unsigned long long)w3 << 32) | (unsigned long long)w2;
  }
  __syncthreads();
#pragma unroll
  for (int p = 0; p < 2; ++p) {
    int q = p * 16 + (lane >> 2);
    int qx = (q & 7) << 3;
    unsigned short* dst =
        ctx + ((size_t)(b * 2048 + q0 + wid * 32 + q)) * 1024 + h * 64;
#pragma unroll
    for (int j = 0; j < 2; ++j) {
      int c = (lane & 3) * 8 + j * 32;
      bf16x8 vv = *(const bf16x8*)&ob[q * 64 + (c ^ qx)];
      __builtin_nontemporal_store(vv, (bf16x8*)(dst + c));
    }
  }
}

// ---------------- launch ----------------
extern "C" void kernel_launch(void* const* d_in, const int* in_sizes, int n_in, void* d_out,
                              int out_size, void* d_ws, size_t ws_size, hipStream_t stream) {
  const float* x = (const float*)d_in[0];
  const int* amask = (const int*)d_in[1];
  const float* ln1w = (const float*)d_in[2];
  const float* ln1b = (const float*)d_in[3];
  const float* Uq = (const float*)d_in[4];
  const float* Vq = (const float*)d_in[5];
  const float* bq = (const float*)d_in[6];
  const float* Uk = (const float*)d_in[7];
  const float* Vk = (const float*)d_in[8];
  const float* bk = (const float*)d_in[9];
  const float* Uv = (const float*)d_in[10];
  const float* Vv = (const float*)d_in[11];
  const float* bv = (const float*)d_in[12];
  const float* Wo = (const float*)d_in[13];
  const float* bo = (const float*)d_in[14];
  const float* ln2w = (const float*)d_in[15];
  const float* ln2b = (const float*)d_in[16];
  const float* Uwi = (const float*)d_in[17];
  const float* Vwi = (const float*)d_in[18];
  const float* bwi = (const float*)d_in[19];
  const float* Uwo = (const float*)d_in[20];
  const float* Vwo = (const float*)d_in[21];
  const float* bwo = (const float*)d_in[22];

  char* ws = (char*)d_ws;
  size_t off = 0;
  auto alloc = [&](size_t bytes) {
    void* p = ws + off;
    off += (bytes + 255) & ~(size_t)255;
    return p;
  };
  unsigned short* xn = (unsigned short*)alloc((size_t)8192 * 1024 * 2);   // also xn2
  unsigned short* Ut = (unsigned short*)alloc((size_t)1536 * 1024 * 2);
  unsigned short* Vt = (unsigned short*)alloc((size_t)48 * 2048 * 2);
  unsigned short* Wob = (unsigned short*)alloc((size_t)1024 * 1024 * 2);
  unsigned short* Uwit = (unsigned short*)alloc((size_t)512 * 1024 * 2);
  unsigned short* Vwit = (unsigned short*)alloc((size_t)8192 * 512 * 2);
  unsigned short* Uwot = (unsigned short*)alloc((size_t)512 * 4096 * 2);
  unsigned short* Vwot = (unsigned short*)alloc((size_t)1024 * 512 * 2);
  unsigned short* qkv = (unsigned short*)alloc((size_t)8192 * 3072 * 2);
  unsigned short* ctx = (unsigned short*)alloc((size_t)8192 * 1024 * 2);
  float* x1 = (float*)alloc((size_t)8192 * 1024 * 4);
  unsigned short* hr = (unsigned short*)alloc((size_t)8192 * 512 * 2);
  unsigned short* gr = (unsigned short*)alloc((size_t)8192 * 512 * 2);
  unsigned short* g = qkv;                 // alias: 64MB over qkv+ctx (dead by FFN)
  unsigned short* xn2 = xn;                // alias: xn dead after QKV
  unsigned short* vT = (unsigned short*)x1;  // alias: x1 written only after attn
  if (off > ws_size) return;               // fail clean instead of faulting
  (void)in_sizes; (void)n_in; (void)out_size;

  dim3 tb(32, 8);
  // weight prep (runs every call; deterministic)
  k_build_ut<<<dim3(32, 48), tb, 0, stream>>>(Uq, Uk, Uv, Ut);
  k_build_vt<<<48, 256, 0, stream>>>(Vq, Vk, Vv, Vt);
  k_f2bf<<<4096, 256, 0, stream>>>(Wo, Wob, 1024 * 1024);
  k_transpose_bf16<<<dim3(512 / 32, 1024 / 32), tb, 0, stream>>>(Uwi, Uwit, 1024, 512);
  k_transpose_bf16<<<dim3(8192 / 32, 512 / 32), tb, 0, stream>>>(Vwi, Vwit, 512, 8192);
  k_transpose_bf16<<<dim3(512 / 32, 4096 / 32), tb, 0, stream>>>(Uwo, Uwot, 4096, 512);
  k_transpose_bf16<<<dim3(1024 / 32, 512 / 32), tb, 0, stream>>>(Vwo, Vwot, 512, 1024);

  // block
  k_layernorm<<<2048, 256, 0, stream>>>(x, ln1w, ln1b, xn);
  k_qkv<<<dim3(12, 64), 256, 0, stream>>>(xn, Ut, Vt, bq, bk, bv, qkv, vT);
  k_attn<<<dim3(16, 64), 256, 0, stream>>>(qkv, vT, amask, ctx);
  k_gemm<2><<<dim3(8, 64), 256, 0, stream>>>(ctx, Wob, bo, x, x1, 1024, 1024);
  k_layernorm<<<2048, 256, 0, stream>>>(x1, ln2w, ln2b, xn2);
  k_gemm64<<<dim3(8, 64), 256, 0, stream>>>(xn2, Uwit, hr, 512, 1024);
  k_gemm_geglu<<<dim3(32, 64), 256, 0, stream>>>(hr, Vwit, bwi, g);
  k_gemm64<<<dim3(8, 64), 256, 0, stream>>>(g, Uwot, gr, 512, 4096);
  k_gemm<2><<<dim3(8, 64), 256, 0, stream>>>(gr, Vwot, bwo, x1, d_out, 1024, 512);
}

// Round 18
// 463.490 us; speedup vs baseline: 1.0290x; 1.0186x over previous
//
#include <hip/hip_runtime.h>
#include <cstdint>

#define DEV __device__ __forceinline__

typedef __attribute__((ext_vector_type(8))) short bf16x8;
typedef __attribute__((ext_vector_type(4))) float f32x4;
typedef __attribute__((ext_vector_type(16))) float f32x16;

#define MFMA(a,b,c) __builtin_amdgcn_mfma_f32_16x16x32_bf16((a),(b),(c),0,0,0)
#define MFMA32(a,b,c) __builtin_amdgcn_mfma_f32_32x32x16_bf16((a),(b),(c),0,0,0)

DEV unsigned short f2bf(float f) {
  union { float f; unsigned u; } v; v.f = f;
  unsigned r = v.u + 0x7fffu + ((v.u >> 16) & 1u);
  return (unsigned short)(r >> 16);
}
DEV float bf2f(unsigned short s) {
  union { unsigned u; float f; } v; v.u = ((unsigned)s) << 16; return v.f;
}
DEV float max3f(float a, float b, float c) { return fmaxf(fmaxf(a, b), c); }

// async global->LDS, 16B per lane. LDS dest is wave-uniform base + lane*16.
DEV void gload16(const unsigned short* g, short* l) {
  __builtin_amdgcn_global_load_lds(
      (const __attribute__((address_space(1))) unsigned*)g,
      (__attribute__((address_space(3))) unsigned*)l, 16, 0, 0);
}

// ---------------- fused weight-prep kernel ----------------
// One launch replaces 7: Ut build, Vt build, Wo f2bf, and 4 fp32->bf16 transposes.
// Each block executes exactly one segment (blockIdx-range dispatch), so the
// transpose __syncthreads stays block-uniform.
DEV void seg_transpose(float (*tile)[33], const float* __restrict__ in,
                       unsigned short* __restrict__ out, int R, int C, int bx, int by,
                       int tid) {
  int c0 = bx * 32, r0 = by * 32;
  int tx = tid & 31, ty = tid >> 5;
#pragma unroll
  for (int i = ty; i < 32; i += 8)
    tile[i][tx] = in[(size_t)(r0 + i) * C + c0 + tx];
  __syncthreads();
#pragma unroll
  for (int i = ty; i < 32; i += 8)
    out[(size_t)(c0 + i) * R + r0 + tx] = f2bf(tile[tx][i]);
}

__global__ __launch_bounds__(256) void k_prep(
    const float* __restrict__ Uq, const float* __restrict__ Uk,
    const float* __restrict__ Uv, const float* __restrict__ Vq,
    const float* __restrict__ Vk, const float* __restrict__ Vv,
    const float* __restrict__ Wo, const float* __restrict__ Uwi,
    const float* __restrict__ Vwi, const float* __restrict__ Uwo,
    const float* __restrict__ Vwo, unsigned short* __restrict__ Ut,
    unsigned short* __restrict__ Vt, unsigned short* __restrict__ Wob,
    unsigned short* __restrict__ Uwit, unsigned short* __restrict__ Vwit,
    unsigned short* __restrict__ Uwot, unsigned short* __restrict__ Vwot) {
  __shared__ float tile[32][33];
  int bid = blockIdx.x;
  int tid = threadIdx.x;
  if (bid < 1536) {  // Ut[proj*512+h*32+r][d] = U[h][d][r]
    int s = bid >> 5, d0 = (bid & 31) * 32;
    int proj = s >> 4, h = s & 15;
    const float* U = (proj == 0) ? Uq : (proj == 1) ? Uk : Uv;
    const float* Us = U + (size_t)h * 1024 * 32;
    int tx = tid & 31, ty = tid >> 5;
#pragma unroll
    for (int i = ty; i < 32; i += 8)
      tile[i][tx] = Us[(size_t)(d0 + i) * 32 + tx];
    __syncthreads();
#pragma unroll
    for (int i = ty; i < 32; i += 8)
      Ut[(size_t)(s * 32 + i) * 1024 + d0 + tx] = f2bf(tile[tx][i]);
    return;
  }
  bid -= 1536;
  if (bid < 48) {  // Vt[ph][dh][r] = V[h][r][dh]
    int ph = bid;
    int proj = ph >> 4, h = ph & 15;
    const float* V = (proj == 0) ? Vq : (proj == 1) ? Vk : Vv;
    const float* Vs = V + (size_t)h * 2048;
#pragma unroll
    for (int idx = tid; idx < 2048; idx += 256) {
      int dh = idx >> 5, r = idx & 31;
      Vt[(size_t)ph * 2048 + idx] = f2bf(Vs[r * 64 + dh]);
    }
    return;
  }
  bid -= 48;
  if (bid < 4096) {  // Wo f2bf (1M elems)
    int i = bid * 256 + tid;
    Wob[i] = f2bf(Wo[i]);
    return;
  }
  bid -= 4096;
  if (bid < 512) {  // Uwi [1024][512] -> Uwit [512][1024]
    seg_transpose(tile, Uwi, Uwit, 1024, 512, bid & 15, bid >> 4, tid);
    return;
  }
  bid -= 512;
  if (bid < 4096) {  // Vwi [512][8192] -> Vwit [8192][512]
    seg_transpose(tile, Vwi, Vwit, 512, 8192, bid & 255, bid >> 8, tid);
    return;
  }
  bid -= 4096;
  if (bid < 2048) {  // Uwo [4096][512] -> Uwot [512][4096]
    seg_transpose(tile, Uwo, Uwot, 4096, 512, bid & 15, bid >> 4, tid);
    return;
  }
  bid -= 2048;
  {  // Vwo [512][1024] -> Vwot [1024][512]  (512 blocks)
    seg_transpose(tile, Vwo, Vwot, 512, 1024, bid & 31, bid >> 5, tid);
  }
}

// ---------------- layernorm: one WAVE per row (4 rows/block, no barrier) ----------------
__global__ __launch_bounds__(256) void k_layernorm(const float* __restrict__ x,
                                                   const float* __restrict__ w,
                                                   const float* __restrict__ b,
                                                   unsigned short* __restrict__ out) {
  int lane = threadIdx.x & 63, wid = threadIdx.x >> 6;
  size_t row = (size_t)blockIdx.x * 4 + wid;
  const float4* xr = (const float4*)(x + row * 1024);
  float4 v[4];
  float s = 0.f, s2 = 0.f;
#pragma unroll
  for (int t = 0; t < 4; ++t) {
    v[t] = xr[lane + t * 64];
    s += v[t].x + v[t].y + v[t].z + v[t].w;
    s2 += v[t].x * v[t].x + v[t].y * v[t].y + v[t].z * v[t].z + v[t].w * v[t].w;
  }
#pragma unroll
  for (int o = 1; o < 64; o <<= 1) { s += __shfl_xor(s, o); s2 += __shfl_xor(s2, o); }
  float mean = s * (1.f / 1024.f);
  float var = s2 * (1.f / 1024.f) - mean * mean;
  float inv = rsqrtf(var + 1e-5f);
  unsigned long long* op = (unsigned long long*)(out + row * 1024);
#pragma unroll
  for (int t = 0; t < 4; ++t) {
    float4 wv = ((const float4*)w)[lane + t * 64];
    float4 bv = ((const float4*)b)[lane + t * 64];
    union { unsigned short u[4]; unsigned long long ll; } o;
    o.u[0] = f2bf((v[t].x - mean) * inv * wv.x + bv.x);
    o.u[1] = f2bf((v[t].y - mean) * inv * wv.y + bv.y);
    o.u[2] = f2bf((v[t].z - mean) * inv * wv.z + bv.z);
    o.u[3] = f2bf((v[t].w - mean) * inv * wv.w + bv.w);
    op[lane + t * 64] = o.ll;
  }
}

// ---------------- GEMM (BK=32, BM=128, BN=128): C = A * Bt^T ----------------
// EPI 0: bf16 out;  1: bf16 out + bias;  2: f32 out + bias + resid
template <int EPI>
__global__ __launch_bounds__(256, 4) void k_gemm(const unsigned short* __restrict__ A,
                                                 const unsigned short* __restrict__ Bt,
                                                 const float* __restrict__ bias,
                                                 const float* __restrict__ resid,
                                                 void* __restrict__ outp, int N, int K) {
  __shared__ short Al[128 * 32];
  __shared__ short Bl[128 * 32];
  int tid = threadIdx.x, lane = tid & 63, wid = tid >> 6;
  int wr = wid >> 1, wc = wid & 1;
  size_t row0 = (size_t)blockIdx.y * 128;
  int col0 = blockIdx.x * 128;
  int arow = lane >> 2, acol = (lane & 3) << 3;
  const unsigned short* Ag = A + (row0 + wid * 32 + arow) * K + acol;
  const unsigned short* Bg = Bt + ((size_t)(col0 + wid * 32 + arow)) * K + acol;
  short* Ald = Al + wid * 1024;
  short* Bld = Bl + wid * 1024;
  f32x4 acc[4][4] = {};
  int fr = lane & 15, fk = (lane >> 4) << 3;
  for (int k0 = 0; k0 < K; k0 += 32) {
    __syncthreads();
    gload16(Ag + k0, Ald);
    gload16(Ag + (size_t)16 * K + k0, Ald + 512);
    gload16(Bg + k0, Bld);
    gload16(Bg + (size_t)16 * K + k0, Bld + 512);
    __syncthreads();
    bf16x8 af[4], bfr[4];
#pragma unroll
    for (int i = 0; i < 4; ++i) {
      af[i] = *(const bf16x8*)&Al[(wr * 64 + i * 16 + fr) * 32 + fk];
      bfr[i] = *(const bf16x8*)&Bl[(wc * 64 + i * 16 + fr) * 32 + fk];
    }
#pragma unroll
    for (int i = 0; i < 4; ++i)
#pragma unroll
      for (int j = 0; j < 4; ++j) acc[i][j] = MFMA(af[i], bfr[j], acc[i][j]);
  }
  int cr = (lane >> 4) << 2, cc = lane & 15;
#pragma unroll
  for (int j = 0; j < 4; ++j) {
    int col = col0 + wc * 64 + j * 16 + cc;
    float bb = (EPI >= 1) ? bias[col] : 0.f;
#pragma unroll
    for (int i = 0; i < 4; ++i) {
#pragma unroll
      for (int r = 0; r < 4; ++r) {
        size_t row = row0 + wr * 64 + i * 16 + cr + r;
        float v = acc[i][j][r] + bb;
        if (EPI == 2)
          ((float*)outp)[row * N + col] = v + resid[row * N + col];
        else
          ((unsigned short*)outp)[row * N + col] = f2bf(v);
      }
    }
  }
}

// ---------------- GEMM64 (BK=32, BM=128, BN=64): for N=512 GEMMs ----------------
__global__ __launch_bounds__(256, 4) void k_gemm64(const unsigned short* __restrict__ A,
                                                   const unsigned short* __restrict__ Bt,
                                                   unsigned short* __restrict__ out,
                                                   int N, int K) {
  __shared__ short Al[128 * 32];
  __shared__ short Bl[64 * 32];
  int tid = threadIdx.x, lane = tid & 63, wid = tid >> 6;
  size_t row0 = (size_t)blockIdx.y * 128;
  int col0 = blockIdx.x * 64;
  int arow = lane >> 2, acol = (lane & 3) << 3;
  const unsigned short* Ag = A + (row0 + wid * 32 + arow) * K + acol;
  const unsigned short* Bg = Bt + ((size_t)(col0 + wid * 16 + arow)) * K + acol;
  short* Ald = Al + wid * 1024;
  short* Bld = Bl + wid * 512;
  f32x4 acc[2][4] = {};
  int fr = lane & 15, fk = (lane >> 4) << 3;
  for (int k0 = 0; k0 < K; k0 += 32) {
    __syncthreads();
    gload16(Ag + k0, Ald);
    gload16(Ag + (size_t)16 * K + k0, Ald + 512);
    gload16(Bg + k0, Bld);
    __syncthreads();
    bf16x8 af[2], bfr[4];
#pragma unroll
    for (int i = 0; i < 2; ++i)
      af[i] = *(const bf16x8*)&Al[(wid * 32 + i * 16 + fr) * 32 + fk];
#pragma unroll
    for (int j = 0; j < 4; ++j)
      bfr[j] = *(const bf16x8*)&Bl[(j * 16 + fr) * 32 + fk];
#pragma unroll
    for (int i = 0; i < 2; ++i)
#pragma unroll
      for (int j = 0; j < 4; ++j) acc[i][j] = MFMA(af[i], bfr[j], acc[i][j]);
  }
  int cr = (lane >> 4) << 2, cc = lane & 15;
#pragma unroll
  for (int j = 0; j < 4; ++j) {
    int col = col0 + j * 16 + cc;
#pragma unroll
    for (int i = 0; i < 2; ++i) {
#pragma unroll
      for (int r = 0; r < 4; ++r) {
        size_t row = row0 + wid * 32 + i * 16 + cr + r;
        out[row * N + col] = f2bf(acc[i][j][r]);
      }
    }
  }
}

// ---------------- fused QKV (BK=32 stage-1): xr = xn @ Ut^T, then per-head
// rank-32 expansion + bias + RoPE; V heads written DIRECTLY to vT (transposed).
__global__ __launch_bounds__(256, 2) void k_qkv(const unsigned short* __restrict__ A,
                                                const unsigned short* __restrict__ Ut,
                                                const unsigned short* __restrict__ Vt,
                                                const float* __restrict__ bq,
                                                const float* __restrict__ bk,
                                                const float* __restrict__ bv,
                                                unsigned short* __restrict__ qkv,
                                                unsigned short* __restrict__ vT) {
  __shared__ short Al[128 * 32];
  __shared__ short Bl[128 * 32];
  __shared__ short Xr[4][64 * 72];
  const int K = 1024, N3 = 3072;
  int tid = threadIdx.x, lane = tid & 63, wid = tid >> 6;
  int wr = wid >> 1, wc = wid & 1;
  size_t row0 = (size_t)blockIdx.y * 128;
  int col0 = blockIdx.x * 128;
  int arow = lane >> 2, acol = (lane & 3) << 3;
  const unsigned short* Ag = A + (row0 + wid * 32 + arow) * K + acol;
  const unsigned short* Bg = Ut + ((size_t)(col0 + wid * 32 + arow)) * K + acol;
  short* Ald = Al + wid * 1024;
  short* Bld = Bl + wid * 1024;
  f32x4 acc[4][4] = {};
  int fr = lane & 15, fk = (lane >> 4) << 3;
  for (int k0 = 0; k0 < K; k0 += 32) {
    __syncthreads();
    gload16(Ag + k0, Ald);
    gload16(Ag + (size_t)16 * K + k0, Ald + 512);
    gload16(Bg + k0, Bld);
    gload16(Bg + (size_t)16 * K + k0, Bld + 512);
    __syncthreads();
    bf16x8 af[4], bfr[4];
#pragma unroll
    for (int i = 0; i < 4; ++i) {
      af[i] = *(const bf16x8*)&Al[(wr * 64 + i * 16 + fr) * 32 + fk];
      bfr[i] = *(const bf16x8*)&Bl[(wc * 64 + i * 16 + fr) * 32 + fk];
    }
#pragma unroll
    for (int i = 0; i < 4; ++i)
#pragma unroll
      for (int j = 0; j < 4; ++j) acc[i][j] = MFMA(af[i], bfr[j], acc[i][j]);
  }
  int cr = (lane >> 4) << 2, cc = lane & 15;
  // bounce xr quadrant (bf16) into per-wave LDS [64 rows][72 cols]
  short* xw = &Xr[wid][0];
#pragma unroll
  for (int j = 0; j < 4; ++j)
#pragma unroll
    for (int i = 0; i < 4; ++i)
#pragma unroll
      for (int r = 0; r < 4; ++r)
        xw[(i * 16 + cr + r) * 72 + j * 16 + cc] = (short)f2bf(acc[i][j][r]);
  // same-wave write->read; compiler inserts lgkmcnt ordering
  int phbase = blockIdx.x * 4 + wc * 2;
  const f32x4 zero4 = {0.f, 0.f, 0.f, 0.f};
#pragma unroll
  for (int h2 = 0; h2 < 2; ++h2) {
    int ph = phbase + h2;
    int proj = ph >> 4, hh = ph & 15;
    bf16x8 af2[4], bf2[4];
#pragma unroll
    for (int i2 = 0; i2 < 4; ++i2)
      af2[i2] = *(const bf16x8*)&xw[(i2 * 16 + fr) * 72 + h2 * 32 + fk];
#pragma unroll
    for (int j2 = 0; j2 < 4; ++j2)
      bf2[j2] = *(const bf16x8*)(Vt + ((size_t)ph * 64 + j2 * 16 + fr) * 32 + fk);
    f32x4 a2[4][4];
#pragma unroll
    for (int i2 = 0; i2 < 4; ++i2)
#pragma unroll
      for (int j2 = 0; j2 < 4; ++j2) a2[i2][j2] = MFMA(af2[i2], bf2[j2], zero4);
    const float* bp = (proj == 0) ? bq : (proj == 1) ? bk : bv;
    if (proj == 2) {  // V: bias + DIRECT transposed write to vT[bh][dh][tok]
      int bq_ = (int)(row0 >> 11);
      int tok0 = (int)(row0 & 2047) + wr * 64;
      unsigned short* vtb = vT + ((size_t)(bq_ * 16 + hh) * 64) * 2048;
#pragma unroll
      for (int j2 = 0; j2 < 4; ++j2) {
        int dh = j2 * 16 + cc;
        float bb = bp[hh * 64 + dh];
        unsigned short* vrow = vtb + (size_t)dh * 2048;
#pragma unroll
        for (int i2 = 0; i2 < 4; ++i2) {
          union { unsigned short u[4]; unsigned long long ll; } o;
#pragma unroll
          for (int r = 0; r < 4; ++r) o.u[r] = f2bf(a2[i2][j2][r] + bb);
          *(unsigned long long*)(vrow + tok0 + i2 * 16 + cr) = o.ll;
        }
      }
    } else {  // Q/K: rotate pairs (dh, dh+32); Q folds 0.125*log2(e)
      int obase = proj * 1024 + hh * 64;
      float sc = (proj == 0) ? 0.18033688011112042f : 1.f;
#pragma unroll
      for (int j2 = 0; j2 < 2; ++j2) {
        int irot = j2 * 16 + cc;  // 0..31
        float freq = __expf((float)irot * -0.28782313662425575f);  // ln(1e4)/32
        float bb1 = bp[hh * 64 + irot];
        float bb2 = bp[hh * 64 + irot + 32];
#pragma unroll
        for (int i2 = 0; i2 < 4; ++i2)
#pragma unroll
          for (int r = 0; r < 4; ++r) {
            size_t row = row0 + wr * 64 + i2 * 16 + cr + r;
            int m = (int)(row & 2047);
            float x1v = a2[i2][j2][r] + bb1;
            float x2v = a2[i2][j2 + 2][r] + bb2;
            float sn, csn;
            __sincosf((float)m * freq, &sn, &csn);
            qkv[row * N3 + obase + irot] = f2bf((x1v * csn - x2v * sn) * sc);
            qkv[row * N3 + obase + irot + 32] = f2bf((x2v * csn + x1v * sn) * sc);
          }
      }
    }
  }
}

// ---------------- GEMM + GEGLU (BK=32): g = gelu_tanh(h1) * h2 ----------------
__global__ __launch_bounds__(256, 2) void k_gemm_geglu(const unsigned short* __restrict__ A,
                                                       const unsigned short* __restrict__ Bt,
                                                       const float* __restrict__ bias,
                                                       unsigned short* __restrict__ out) {
  __shared__ short Al[128 * 32];
  __shared__ short B1l[128 * 32];
  __shared__ short B2l[128 * 32];
  const int K = 512;
  int tid = threadIdx.x, lane = tid & 63, wid = tid >> 6;
  int wr = wid >> 1, wc = wid & 1;
  size_t row0 = (size_t)blockIdx.y * 128;
  int col0 = blockIdx.x * 128;
  int arow = lane >> 2, acol = (lane & 3) << 3;
  const unsigned short* Ag = A + (row0 + wid * 32 + arow) * K + acol;
  const unsigned short* B1g = Bt + ((size_t)(col0 + wid * 32 + arow)) * K + acol;
  const unsigned short* B2g = Bt + ((size_t)(col0 + 4096 + wid * 32 + arow)) * K + acol;
  short* Ald = Al + wid * 1024;
  short* B1d = B1l + wid * 1024;
  short* B2d = B2l + wid * 1024;
  f32x4 acc1[4][4] = {}, acc2[4][4] = {};
  int fr = lane & 15, fk = (lane >> 4) << 3;
  for (int k0 = 0; k0 < K; k0 += 32) {
    __syncthreads();
    gload16(Ag + k0, Ald);
    gload16(Ag + (size_t)16 * K + k0, Ald + 512);
    gload16(B1g + k0, B1d);
    gload16(B1g + (size_t)16 * K + k0, B1d + 512);
    gload16(B2g + k0, B2d);
    gload16(B2g + (size_t)16 * K + k0, B2d + 512);
    __syncthreads();
    bf16x8 af[4], b1f[4], b2f[4];
#pragma unroll
    for (int i = 0; i < 4; ++i) {
      af[i] = *(const bf16x8*)&Al[(wr * 64 + i * 16 + fr) * 32 + fk];
      b1f[i] = *(const bf16x8*)&B1l[(wc * 64 + i * 16 + fr) * 32 + fk];
      b2f[i] = *(const bf16x8*)&B2l[(wc * 64 + i * 16 + fr) * 32 + fk];
    }
#pragma unroll
    for (int i = 0; i < 4; ++i)
#pragma unroll
      for (int j = 0; j < 4; ++j) {
        acc1[i][j] = MFMA(af[i], b1f[j], acc1[i][j]);
        acc2[i][j] = MFMA(af[i], b2f[j], acc2[i][j]);
      }
  }
  int cr = (lane >> 4) << 2, cc = lane & 15;
#pragma unroll
  for (int j = 0; j < 4; ++j) {
    int col = col0 + wc * 64 + j * 16 + cc;
    float bb1 = bias[col], bb2 = bias[col + 4096];
#pragma unroll
    for (int i = 0; i < 4; ++i) {
#pragma unroll
      for (int r = 0; r < 4; ++r) {
        size_t row = row0 + wr * 64 + i * 16 + cr + r;
        float h1 = acc1[i][j][r] + bb1;
        float h2 = acc2[i][j][r] + bb2;
        float u = 0.7978845608028654f * (h1 + 0.044715f * h1 * h1 * h1);
        float e = __expf(2.f * u);
        float th = 1.f - 2.f / (e + 1.f);
        float gv = 0.5f * h1 * (1.f + th) * h2;
        out[row * 4096 + col] = f2bf(gv);
      }
    }
  }
}

// ---------------- flash attention: 32x32x16 MFMA, double-buffered K/V ----------------
#define KIX(r, c) ((r) * 64 + ((c) ^ (((r) & 7) << 3)))

__global__ __launch_bounds__(256, 4) void k_attn(const unsigned short* __restrict__ qkv,
                                                 const unsigned short* __restrict__ vT,
                                                 const int* __restrict__ mask,
                                                 unsigned short* __restrict__ ctx) {
  __shared__ short pool[16384];  // [buf0: K 4096 | V 4096][buf1: K 4096 | V 4096]
  int bh = blockIdx.y, b = bh >> 4, h = bh & 15;
  int q0 = blockIdx.x << 7;
  int tid = threadIdx.x, lane = tid & 63, wid = tid >> 6;
  int qi = lane & 31, hi = lane >> 5;
  const unsigned short* qrow =
      qkv + ((size_t)(b * 2048 + q0 + wid * 32 + qi)) * 3072 + h * 64 + hi * 8;
  bf16x8 qa[4];
#pragma unroll
  for (int c = 0; c < 4; ++c) qa[c] = *(const bf16x8*)(qrow + c * 16);
  float m_r = -1e30f, l_r = 0.f;
  f32x16 oacc0 = {}, oacc1 = {};
  int srw = lane >> 3;
  int schx = ((lane & 7) ^ srw) << 3;
  int rb = wid * 16;
  const unsigned short* kgb =
      qkv + ((size_t)(b * 2048 + rb + srw)) * 3072 + 1024 + h * 64 + schx;
  const unsigned short* vgb = vT + ((size_t)(bh * 64 + rb + srw)) * 2048 + schx;
  const int* mbase = mask + b * 2048;
  const f32x16 zero16 = {};
  unsigned mbits = 0;
  for (int t = 0; t < 32; ++t) {
    int mv = mbase[t * 64 + lane];
    if (__ballot(mv == 0) != 0ull) mbits |= (1u << t);
  }
  {
    short* kb0 = pool + rb * 64;
    short* vb0 = pool + 4096 + rb * 64;
    gload16(kgb, kb0);
    gload16(kgb + (size_t)8 * 3072, kb0 + 512);
    gload16(vgb, vb0);
    gload16(vgb + (size_t)8 * 2048, vb0 + 512);
  }
  int cur = 0;
  for (int k0 = 0; k0 < 2048; k0 += 64) {
    __syncthreads();
    if (k0 + 64 < 2048) {
      short* kn = pool + (cur ^ 1) * 8192 + rb * 64;
      short* vn = pool + (cur ^ 1) * 8192 + 4096 + rb * 64;
      gload16(kgb + (size_t)(k0 + 64) * 3072, kn);
      gload16(kgb + (size_t)(k0 + 72) * 3072, kn + 512);
      gload16(vgb + (k0 + 64), vn);
      gload16(vgb + (size_t)8 * 2048 + (k0 + 64), vn + 512);
    }
    const short* Kl = pool + cur * 8192;
    const short* Vl = pool + cur * 8192 + 4096;
    bool masked = (mbits >> (k0 >> 6)) & 1;
#pragma unroll
    for (int kt = 0; kt < 2; ++kt) {
      f32x16 s = zero16;
      __builtin_amdgcn_s_setprio(1);
#pragma unroll
      for (int c = 0; c < 4; ++c) {
        bf16x8 kf = *(const bf16x8*)&Kl[KIX(kt * 32 + qi, c * 16 + hi * 8)];
        s = MFMA32(kf, qa[c], s);
      }
      __builtin_amdgcn_s_setprio(0);
      if (masked) {
#pragma unroll
        for (int t = 0; t < 4; ++t) {
          int mi = k0 + kt * 32 + 8 * t + 4 * hi;
#pragma unroll
          for (int r = 0; r < 4; ++r)
            s[t * 4 + r] += (mbase[mi + r] == 0) ? -1e30f : 0.f;
        }
      }
      float t0 = max3f(s[0], s[1], s[2]);
      float t1 = max3f(s[3], s[4], s[5]);
      float t2 = max3f(s[6], s[7], s[8]);
      float t3 = max3f(s[9], s[10], s[11]);
      float t4 = max3f(s[12], s[13], s[14]);
      float t5 = fmaxf(t0, s[15]);
      float pmax = max3f(max3f(t5, t1, t2), t3, t4);
      pmax = fmaxf(pmax, __shfl_xor(pmax, 32));
      if (!__all(pmax - m_r <= 8.f)) {
        float mn = fmaxf(m_r, pmax);
        float fac = exp2f(m_r - mn);
        m_r = mn;
        l_r *= fac;
#pragma unroll
        for (int r = 0; r < 16; ++r) { oacc0[r] *= fac; oacc1[r] *= fac; }
      }
#pragma unroll
      for (int r = 0; r < 16; ++r) s[r] = exp2f(s[r] - m_r);
      float su0 = (s[0] + s[1]) + (s[2] + s[3]);
      float su1 = (s[4] + s[5]) + (s[6] + s[7]);
      float su2 = (s[8] + s[9]) + (s[10] + s[11]);
      float su3 = (s[12] + s[13]) + (s[14] + s[15]);
      l_r += (su0 + su1) + (su2 + su3);
      unsigned pk[8];
#pragma unroll
      for (int w = 0; w < 8; ++w)
        asm("v_cvt_pk_bf16_f32 %0, %1, %2" : "=v"(pk[w]) : "v"(s[2 * w]), "v"(s[2 * w + 1]));
      unsigned a0 = pk[0], b0 = pk[2];
      unsigned a1 = pk[1], b1 = pk[3];
      unsigned a2 = pk[4], b2 = pk[6];
      unsigned a3 = pk[5], b3 = pk[7];
      asm("v_permlane32_swap_b32 %0, %1" : "+v"(a0), "+v"(b0));
      asm("v_permlane32_swap_b32 %0, %1" : "+v"(a1), "+v"(b1));
      asm("v_permlane32_swap_b32 %0, %1" : "+v"(a2), "+v"(b2));
      asm("v_permlane32_swap_b32 %0, %1" : "+v"(a3), "+v"(b3));
      union { unsigned u[4]; bf16x8 v; } pb0, pb1;
      pb0.u[0] = a0; pb0.u[1] = a1; pb0.u[2] = b0; pb0.u[3] = b1;
      pb1.u[0] = a2; pb1.u[1] = a3; pb1.u[2] = b2; pb1.u[3] = b3;
      __builtin_amdgcn_s_setprio(1);
      {
        bf16x8 vf00 = *(const bf16x8*)&Vl[KIX(qi, kt * 32 + hi * 8)];
        bf16x8 vf01 = *(const bf16x8*)&Vl[KIX(qi, kt * 32 + 16 + hi * 8)];
        oacc0 = MFMA32(vf00, pb0.v, oacc0);
        oacc0 = MFMA32(vf01, pb1.v, oacc0);
        bf16x8 vf10 = *(const bf16x8*)&Vl[KIX(32 + qi, kt * 32 + hi * 8)];
        bf16x8 vf11 = *(const bf16x8*)&Vl[KIX(32 + qi, kt * 32 + 16 + hi * 8)];
        oacc1 = MFMA32(vf10, pb0.v, oacc1);
        oacc1 = MFMA32(vf11, pb1.v, oacc1);
      }
      __builtin_amdgcn_s_setprio(0);
    }
    cur ^= 1;
  }
  l_r += __shfl_xor(l_r, 32);
  float invl = 1.f / l_r;
  __syncthreads();
  short* ob = pool + wid * 2048;
  int xsw = (qi & 7) << 3;
#pragma unroll
  for (int t = 0; t < 4; ++t) {
    int d = t * 8 + 4 * hi;
    float a0 = oacc0[4 * t] * invl, a1 = oacc0[4 * t + 1] * invl;
    float a2 = oacc0[4 * t + 2] * invl, a3 = oacc0[4 * t + 3] * invl;
    unsigned w0, w1;
    asm("v_cvt_pk_bf16_f32 %0, %1, %2" : "=v"(w0) : "v"(a0), "v"(a1));
    asm("v_cvt_pk_bf16_f32 %0, %1, %2" : "=v"(w1) : "v"(a2), "v"(a3));
    *(unsigned long long*)&ob[qi * 64 + (d ^ xsw)] =
        ((unsigned long long)w1 << 32) | (unsigned long long)w0;
    float c0 = oacc1[4 * t] * invl, c1 = oacc1[4 * t + 1] * invl;
    float c2 = oacc1[4 * t + 2] * invl, c3 = oacc1[4 * t + 3] * invl;
    unsigned w2, w3;
    asm("v_cvt_pk_bf16_f32 %0, %1, %2" : "=v"(w2) : "v"(c0), "v"(c1));
    asm("v_cvt_pk_bf16_f32 %0, %1, %2" : "=v"(w3) : "v"(c2), "v"(c3));
    *(unsigned long long*)&ob[qi * 64 + ((d + 32) ^ xsw)] =
        ((unsigned long long)w3 << 32) | (unsigned long long)w2;
  }
  __syncthreads();
#pragma unroll
  for (int p = 0; p < 2; ++p) {
    int q = p * 16 + (lane >> 2);
    int qx = (q & 7) << 3;
    unsigned short* dst =
        ctx + ((size_t)(b * 2048 + q0 + wid * 32 + q)) * 1024 + h * 64;
#pragma unroll
    for (int j = 0; j < 2; ++j) {
      int c = (lane & 3) * 8 + j * 32;
      bf16x8 vv = *(const bf16x8*)&ob[q * 64 + (c ^ qx)];
      __builtin_nontemporal_store(vv, (bf16x8*)(dst + c));
    }
  }
}

// ---------------- launch ----------------
extern "C" void kernel_launch(void* const* d_in, const int* in_sizes, int n_in, void* d_out,
                              int out_size, void* d_ws, size_t ws_size, hipStream_t stream) {
  const float* x = (const float*)d_in[0];
  const int* amask = (const int*)d_in[1];
  const float* ln1w = (const float*)d_in[2];
  const float* ln1b = (const float*)d_in[3];
  const float* Uq = (const float*)d_in[4];
  const float* Vq = (const float*)d_in[5];
  const float* bq = (const float*)d_in[6];
  const float* Uk = (const float*)d_in[7];
  const float* Vk = (const float*)d_in[8];
  const float* bk = (const float*)d_in[9];
  const float* Uv = (const float*)d_in[10];
  const float* Vv = (const float*)d_in[11];
  const float* bv = (const float*)d_in[12];
  const float* Wo = (const float*)d_in[13];
  const float* bo = (const float*)d_in[14];
  const float* ln2w = (const float*)d_in[15];
  const float* ln2b = (const float*)d_in[16];
  const float* Uwi = (const float*)d_in[17];
  const float* Vwi = (const float*)d_in[18];
  const float* bwi = (const float*)d_in[19];
  const float* Uwo = (const float*)d_in[20];
  const float* Vwo = (const float*)d_in[21];
  const float* bwo = (const float*)d_in[22];

  char* ws = (char*)d_ws;
  size_t off = 0;
  auto alloc = [&](size_t bytes) {
    void* p = ws + off;
    off += (bytes + 255) & ~(size_t)255;
    return p;
  };
  unsigned short* xn = (unsigned short*)alloc((size_t)8192 * 1024 * 2);   // also xn2
  unsigned short* Ut = (unsigned short*)alloc((size_t)1536 * 1024 * 2);
  unsigned short* Vt = (unsigned short*)alloc((size_t)48 * 2048 * 2);
  unsigned short* Wob = (unsigned short*)alloc((size_t)1024 * 1024 * 2);
  unsigned short* Uwit = (unsigned short*)alloc((size_t)512 * 1024 * 2);
  unsigned short* Vwit = (unsigned short*)alloc((size_t)8192 * 512 * 2);
  unsigned short* Uwot = (unsigned short*)alloc((size_t)512 * 4096 * 2);
  unsigned short* Vwot = (unsigned short*)alloc((size_t)1024 * 512 * 2);
  unsigned short* qkv = (unsigned short*)alloc((size_t)8192 * 3072 * 2);
  unsigned short* ctx = (unsigned short*)alloc((size_t)8192 * 1024 * 2);
  float* x1 = (float*)alloc((size_t)8192 * 1024 * 4);
  unsigned short* hr = (unsigned short*)alloc((size_t)8192 * 512 * 2);
  unsigned short* gr = (unsigned short*)alloc((size_t)8192 * 512 * 2);
  unsigned short* g = qkv;                 // alias: 64MB over qkv+ctx (dead by FFN)
  unsigned short* xn2 = xn;                // alias: xn dead after QKV
  unsigned short* vT = (unsigned short*)x1;  // alias: x1 written only after attn
  if (off > ws_size) return;               // fail clean instead of faulting
  (void)in_sizes; (void)n_in; (void)out_size;

  // fused weight prep: one launch (Ut 1536 | Vt 48 | Wob 4096 | Uwit 512 |
  // Vwit 4096 | Uwot 2048 | Vwot 512 = 12848 blocks)
  k_prep<<<12848, 256, 0, stream>>>(Uq, Uk, Uv, Vq, Vk, Vv, Wo, Uwi, Vwi, Uwo, Vwo,
                                    Ut, Vt, Wob, Uwit, Vwit, Uwot, Vwot);

  // block
  k_layernorm<<<2048, 256, 0, stream>>>(x, ln1w, ln1b, xn);
  k_qkv<<<dim3(12, 64), 256, 0, stream>>>(xn, Ut, Vt, bq, bk, bv, qkv, vT);
  k_attn<<<dim3(16, 64), 256, 0, stream>>>(qkv, vT, amask, ctx);
  k_gemm<2><<<dim3(8, 64), 256, 0, stream>>>(ctx, Wob, bo, x, x1, 1024, 1024);
  k_layernorm<<<2048, 256, 0, stream>>>(x1, ln2w, ln2b, xn2);
  k_gemm64<<<dim3(8, 64), 256, 0, stream>>>(xn2, Uwit, hr, 512, 1024);
  k_gemm_geglu<<<dim3(32, 64), 256, 0, stream>>>(hr, Vwit, bwi, g);
  k_gemm64<<<dim3(8, 64), 256, 0, stream>>>(g, Uwot, gr, 512, 4096);
  k_gemm<2><<<dim3(8, 64), 256, 0, stream>>>(gr, Vwot, bwo, x1, d_out, 1024, 512);
}